// Round 2
// baseline (1517.769 us; speedup 1.0000x reference)
//
#include <hip/hip_runtime.h>

// SelfAttentiveLBLBiLM on MI355X — round 2: fp32 I/O (reference dtypes),
// bf16 internal pipeline. Round-1 NaN fingerprinted fp32 buffers being read
// as bf16 (random low mantissa bits -> 0xFF exponents -> NaN operands).
//
// Pipeline per side: QKV gemms -> windowed attention (win=10) -> out-proj gemm
// -> rel add -> highway x2 (gemm + gate). GEMM = SIMT 128x128, 8x8/thread,
// fp32 accumulate, bf16 in, bf16 out (fp32 bias read in epilogue).

#define B_ 8
#define S_ 1024
#define D_ 512
#define H_ 8
#define DK_ 64
#define WIDTH_ 8
#define S2_ 1040
#define NHW_ 2

__device__ __forceinline__ float us2f(unsigned short u) {
  union { unsigned int i; float f; } c; c.i = ((unsigned int)u) << 16; return c.f;
}
__device__ __forceinline__ unsigned short f2us(float f) {
  union { float f; unsigned int i; } c; c.f = f;
  unsigned int x = c.i;
  return (unsigned short)((x + 0x7fffu + ((x >> 16) & 1u)) >> 16);
}
__device__ __forceinline__ unsigned int pack2(float a, float b) {
  return (unsigned int)f2us(a) | ((unsigned int)f2us(b) << 16);
}

// ---------------------------------------------------------------------------
// fp32 -> bf16 conversion, 8 elems/thread. n8 = n/8 thread count.
__global__ __launch_bounds__(256) void k_cvt_f2b(
    const float* __restrict__ src, unsigned short* __restrict__ dst, int n8)
{
  int gid = blockIdx.x * 256 + threadIdx.x;
  if (gid >= n8) return;
  const float4* s = reinterpret_cast<const float4*>(src) + (size_t)gid * 2;
  float4 a = s[0], b = s[1];
  uint4 o;
  o.x = pack2(a.x, a.y); o.y = pack2(a.z, a.w);
  o.z = pack2(b.x, b.y); o.w = pack2(b.z, b.w);
  *(reinterpret_cast<uint4*>(dst) + gid) = o;
}

// ---------------------------------------------------------------------------
// new_in = concat(left_pad, x, right_pad) along sequence, (B,S2,D).
// fp32 sources -> bf16 dest. 8 elems/thread. grid: B*S2*D/8/256 = 2080 blocks.
__global__ __launch_bounds__(256) void k_build_new_in(
    const float* __restrict__ x,
    const float* __restrict__ lpad,
    const float* __restrict__ rpad,
    unsigned short* __restrict__ nin)
{
  int gid = blockIdx.x * 256 + threadIdx.x;
  int c8 = (gid & 63) << 3;       // D/8 = 64 chunks per row
  int row = gid >> 6;             // b*S2 + t
  if (row >= B_ * S2_) return;
  int b = row / S2_;
  int t = row - b * S2_;
  const float* src;
  if (t < WIDTH_)            src = lpad + (size_t)t * D_ + c8;
  else if (t >= S_ + WIDTH_) src = rpad + (size_t)(t - S_ - WIDTH_) * D_ + c8;
  else                       src = x + ((size_t)b * S_ + (t - WIDTH_)) * D_ + c8;
  float4 a = *reinterpret_cast<const float4*>(src);
  float4 c = *reinterpret_cast<const float4*>(src + 4);
  uint4 o;
  o.x = pack2(a.x, a.y); o.y = pack2(a.z, a.w);
  o.z = pack2(c.x, c.y); o.w = pack2(c.z, c.w);
  *reinterpret_cast<uint4*>(nin + (size_t)row * D_ + c8) = o;
}

// ---------------------------------------------------------------------------
// GEMM: C[M,N] = A[M,K] @ W[K,N] + bias[N]; bf16 A/W/C, fp32 bias + accum.
// BM=BN=128, BK=16, 256 threads, 8x8 microtile. Requires M%128==N%128==K%16==0.
__global__ __launch_bounds__(256) void k_gemm_bf16(
    const unsigned short* __restrict__ A,
    const unsigned short* __restrict__ W,
    const float* __restrict__ bias,
    unsigned short* __restrict__ C,
    int M, int N, int K)
{
  __shared__ float As[16][132];   // +4 pad keeps 16B alignment for b128 reads
  __shared__ float Ws[16][128];

  const int tid = threadIdx.x;
  const int bm = blockIdx.y * 128;
  const int bn = blockIdx.x * 128;
  const int tx = tid & 15;        // n direction
  const int ty = tid >> 4;        // m direction

  const int arow = tid >> 1;          // 0..127
  const int acol = (tid & 1) << 3;    // 0 or 8
  const int wrow = tid >> 4;          // 0..15
  const int wcol = (tid & 15) << 3;   // 0..120

  const unsigned short* Ap = A + (size_t)(bm + arow) * K + acol;
  const unsigned short* Wp = W + (size_t)wrow * N + bn + wcol;

  float acc[8][8];
  #pragma unroll
  for (int i = 0; i < 8; ++i)
    #pragma unroll
    for (int j = 0; j < 8; ++j) acc[i][j] = 0.f;

  for (int k0 = 0; k0 < K; k0 += 16) {
    uint4 a8 = *reinterpret_cast<const uint4*>(Ap + k0);
    uint4 w8 = *reinterpret_cast<const uint4*>(Wp + (size_t)k0 * N);
    unsigned int aw[4] = {a8.x, a8.y, a8.z, a8.w};
    unsigned int ww[4] = {w8.x, w8.y, w8.z, w8.w};
    #pragma unroll
    for (int c = 0; c < 4; ++c) {
      As[acol + 2*c    ][arow] = us2f((unsigned short)(aw[c] & 0xffffu));
      As[acol + 2*c + 1][arow] = us2f((unsigned short)(aw[c] >> 16));
      Ws[wrow][wcol + 2*c    ] = us2f((unsigned short)(ww[c] & 0xffffu));
      Ws[wrow][wcol + 2*c + 1] = us2f((unsigned short)(ww[c] >> 16));
    }
    __syncthreads();
    #pragma unroll
    for (int k = 0; k < 16; ++k) {
      float am[8], wn[8];
      #pragma unroll
      for (int i = 0; i < 8; ++i) am[i] = As[k][ty * 8 + i];
      #pragma unroll
      for (int j = 0; j < 8; ++j) wn[j] = Ws[k][tx * 8 + j];
      #pragma unroll
      for (int i = 0; i < 8; ++i)
        #pragma unroll
        for (int j = 0; j < 8; ++j)
          acc[i][j] += am[i] * wn[j];
    }
    __syncthreads();
  }

  float bv[8];
  #pragma unroll
  for (int j = 0; j < 8; ++j) bv[j] = bias[bn + tx * 8 + j];

  #pragma unroll
  for (int i = 0; i < 8; ++i) {
    unsigned short* Cp = C + (size_t)(bm + ty * 8 + i) * N + bn + tx * 8;
    uint4 o;
    o.x = pack2(acc[i][0] + bv[0], acc[i][1] + bv[1]);
    o.y = pack2(acc[i][2] + bv[2], acc[i][3] + bv[3]);
    o.z = pack2(acc[i][4] + bv[4], acc[i][5] + bv[5]);
    o.w = pack2(acc[i][6] + bv[6], acc[i][7] + bv[7]);
    *reinterpret_cast<uint4*>(Cp) = o;
  }
}

// ---------------------------------------------------------------------------
// Windowed attention. One wave per (b,i,h); lane = d within head (DK=64).
// dir==0 (left): j in [i-9, i]; dir==1 (right): j in [i, i+9]. 1/sqrt(64)=0.125.
__global__ __launch_bounds__(256) void k_attn_window(
    const unsigned short* __restrict__ q,
    const unsigned short* __restrict__ k,
    const unsigned short* __restrict__ v,
    unsigned short* __restrict__ ctx,
    int dir)
{
  int wid = (blockIdx.x * 256 + threadIdx.x) >> 6;
  int lane = threadIdx.x & 63;
  if (wid >= B_ * S2_ * H_) return;
  int h = wid & (H_ - 1);
  int i = (wid >> 3) % S2_;
  int b = wid / (S2_ * H_);

  const size_t bbase = (size_t)b * S2_ * D_;
  const size_t col = (size_t)h * DK_ + lane;
  float qd = us2f(q[bbase + (size_t)i * D_ + col]);

  float sc[10];
  float mx = -1e30f;
  #pragma unroll
  for (int t = 0; t < 10; ++t) {
    int j = (dir == 0) ? (i - 9 + t) : (i + t);
    float s = -1e30f;
    if (j >= 0 && j < S2_) {
      float kd = us2f(k[bbase + (size_t)j * D_ + col]);
      float p = qd * kd;
      #pragma unroll
      for (int off = 32; off > 0; off >>= 1) p += __shfl_xor(p, off);
      s = p * 0.125f;
    }
    sc[t] = s;
    mx = fmaxf(mx, s);
  }
  float denom = 0.f;
  #pragma unroll
  for (int t = 0; t < 10; ++t) {
    sc[t] = (sc[t] > -1e29f) ? __expf(sc[t] - mx) : 0.f;
    denom += sc[t];
  }
  float inv = 1.f / denom;
  float o = 0.f;
  #pragma unroll
  for (int t = 0; t < 10; ++t) {
    int j = (dir == 0) ? (i - 9 + t) : (i + t);
    if (j >= 0 && j < S2_ && sc[t] > 0.f) {
      float vd = us2f(v[bbase + (size_t)j * D_ + col]);
      o += sc[t] * vd;
    }
  }
  ctx[bbase + (size_t)i * D_ + col] = f2us(o * inv);
}

// ---------------------------------------------------------------------------
// hwx[b,s,:] = proj[b, WIDTH+s, :] + sum_{j=0..8} wrel[j] * nin[b, off+j+s, :]
// off = 0 (left) or WIDTH (right). 8 elems/thread. wrel is fp32 (9 elems).
__global__ __launch_bounds__(256) void k_rel_add(
    const unsigned short* __restrict__ proj,   // (B,S2,D) bf16
    const unsigned short* __restrict__ nin,    // (B,S2,D) bf16
    const float* __restrict__ wrel,            // 9 fp32
    unsigned short* __restrict__ hwx,          // (B,S,D) bf16
    int off)
{
  int gid = blockIdx.x * 256 + threadIdx.x;
  int c8 = (gid & 63) << 3;
  int row = gid >> 6;                 // b*S + s
  if (row >= B_ * S_) return;
  int b = row >> 10;
  int s = row & (S_ - 1);

  float acc[8];
  uint4 p4 = *reinterpret_cast<const uint4*>(
      proj + ((size_t)b * S2_ + WIDTH_ + s) * D_ + c8);
  unsigned int pw[4] = {p4.x, p4.y, p4.z, p4.w};
  #pragma unroll
  for (int c = 0; c < 4; ++c) {
    acc[2*c]     = us2f((unsigned short)(pw[c] & 0xffffu));
    acc[2*c + 1] = us2f((unsigned short)(pw[c] >> 16));
  }
  #pragma unroll
  for (int j = 0; j < 9; ++j) {
    float w = wrel[j];
    uint4 n4 = *reinterpret_cast<const uint4*>(
        nin + ((size_t)b * S2_ + off + j + s) * D_ + c8);
    unsigned int nw[4] = {n4.x, n4.y, n4.z, n4.w};
    #pragma unroll
    for (int c = 0; c < 4; ++c) {
      acc[2*c]     += w * us2f((unsigned short)(nw[c] & 0xffffu));
      acc[2*c + 1] += w * us2f((unsigned short)(nw[c] >> 16));
    }
  }
  uint4 o;
  o.x = pack2(acc[0], acc[1]); o.y = pack2(acc[2], acc[3]);
  o.z = pack2(acc[4], acc[5]); o.w = pack2(acc[6], acc[7]);
  *reinterpret_cast<uint4*>(hwx + (size_t)row * D_ + c8) = o;
}

// ---------------------------------------------------------------------------
// Highway gate: r = g*x + (1-g)*relu(nl), nl = proj[:, :D], g = sigmoid(proj[:, D:]).
// FP32OUT=false: write bf16 to outb (ld=D). FP32OUT=true: write fp32 to outf
// (ld=2D, column offset coff) -> final d_out.
template <bool FP32OUT>
__global__ __launch_bounds__(256) void k_hw_combine(
    const unsigned short* __restrict__ x,      // (B*S, D) bf16
    const unsigned short* __restrict__ proj,   // (B*S, 2D) bf16
    unsigned short* __restrict__ outb,
    float* __restrict__ outf,
    int coff)
{
  int gid = blockIdx.x * 256 + threadIdx.x;
  int c8 = (gid & 63) << 3;
  int row = gid >> 6;
  if (row >= B_ * S_) return;

  uint4 xv = *reinterpret_cast<const uint4*>(x + (size_t)row * D_ + c8);
  uint4 nv = *reinterpret_cast<const uint4*>(proj + (size_t)row * (2 * D_) + c8);
  uint4 gv = *reinterpret_cast<const uint4*>(proj + (size_t)row * (2 * D_) + D_ + c8);
  unsigned int xw[4] = {xv.x, xv.y, xv.z, xv.w};
  unsigned int nw[4] = {nv.x, nv.y, nv.z, nv.w};
  unsigned int gw[4] = {gv.x, gv.y, gv.z, gv.w};
  float r[8];
  #pragma unroll
  for (int c = 0; c < 4; ++c) {
    #pragma unroll
    for (int hh = 0; hh < 2; ++hh) {
      unsigned short xu = hh ? (unsigned short)(xw[c] >> 16) : (unsigned short)(xw[c] & 0xffffu);
      unsigned short nu = hh ? (unsigned short)(nw[c] >> 16) : (unsigned short)(nw[c] & 0xffffu);
      unsigned short gu = hh ? (unsigned short)(gw[c] >> 16) : (unsigned short)(gw[c] & 0xffffu);
      float xf = us2f(xu);
      float nl = fmaxf(us2f(nu), 0.f);
      float g  = 1.f / (1.f + __expf(-us2f(gu)));
      r[2*c + hh] = g * xf + (1.f - g) * nl;
    }
  }
  if (FP32OUT) {
    float* Op = outf + (size_t)row * (2 * D_) + coff + c8;
    *reinterpret_cast<float4*>(Op)     = make_float4(r[0], r[1], r[2], r[3]);
    *reinterpret_cast<float4*>(Op + 4) = make_float4(r[4], r[5], r[6], r[7]);
  } else {
    uint4 o;
    o.x = pack2(r[0], r[1]); o.y = pack2(r[2], r[3]);
    o.z = pack2(r[4], r[5]); o.w = pack2(r[6], r[7]);
    *reinterpret_cast<uint4*>(outb + (size_t)row * D_ + c8) = o;
  }
}

// ---------------------------------------------------------------------------
extern "C" void kernel_launch(void* const* d_in, const int* in_sizes, int n_in,
                              void* d_out, int out_size, void* d_ws, size_t ws_size,
                              hipStream_t stream) {
  const float* x    = (const float*)d_in[0];
  const float* lW   = (const float*)d_in[1];
  const float* lb   = (const float*)d_in[2];
  const float* rW   = (const float*)d_in[3];
  const float* rb   = (const float*)d_in[4];
  const float* lpad = (const float*)d_in[5];
  const float* rpad = (const float*)d_in[6];
  const float* lw   = (const float*)d_in[7];
  const float* rw   = (const float*)d_in[8];
  const float* lhwW = (const float*)d_in[9];
  const float* lhwb = (const float*)d_in[10];
  const float* rhwW = (const float*)d_in[11];
  const float* rhwb = (const float*)d_in[12];
  float* out = (float*)d_out;
  unsigned short* ws = (unsigned short*)d_ws;

  const size_t NIN  = (size_t)B_ * S2_ * D_;        // 4,259,840
  const size_t NATT = (size_t)4 * D_ * D_;          // 1,048,576 (attn W per side)
  const size_t NHWW = (size_t)NHW_ * D_ * 2 * D_;   // 1,048,576 (hw W per side)
  unsigned short* nin  = ws;
  unsigned short* qb   = nin + NIN;
  unsigned short* kb   = qb + NIN;
  unsigned short* vb   = kb + NIN;
  unsigned short* cb   = vb + NIN;
  unsigned short* hwp  = cb + NIN;                  // B*S*2D = 8,388,608
  unsigned short* lWc  = hwp + (size_t)B_ * S_ * 2 * D_;
  unsigned short* rWc  = lWc + NATT;
  unsigned short* lhWc = rWc + NATT;
  unsigned short* rhWc = lhWc + NHWW;
  // total ws: 33,882,112 bf16 = 67.8 MB

  const int MQ = B_ * S2_;   // 8320
  const int MH = B_ * S_;    // 8192

  // weight conversions (fp32 -> bf16)
  k_cvt_f2b<<<(int)(NATT / 8 / 256), 256, 0, stream>>>(lW, lWc, (int)(NATT / 8));
  k_cvt_f2b<<<(int)(NATT / 8 / 256), 256, 0, stream>>>(rW, rWc, (int)(NATT / 8));
  k_cvt_f2b<<<(int)(NHWW / 8 / 256), 256, 0, stream>>>(lhwW, lhWc, (int)(NHWW / 8));
  k_cvt_f2b<<<(int)(NHWW / 8 / 256), 256, 0, stream>>>(rhwW, rhWc, (int)(NHWW / 8));

  k_build_new_in<<<2080, 256, 0, stream>>>(x, lpad, rpad, nin);

  for (int side = 0; side < 2; ++side) {
    const unsigned short* W  = side ? rWc : lWc;
    const float* bb          = side ? rb : lb;
    const float* wr          = side ? rw : lw;
    const unsigned short* hW = side ? rhWc : lhWc;
    const float* hb          = side ? rhwb : lhwb;

    dim3 gq(D_ / 128, MQ / 128);     // (4, 65)
    k_gemm_bf16<<<gq, 256, 0, stream>>>(nin, W + 0 * D_ * D_, bb + 0 * D_, qb, MQ, D_, D_);
    k_gemm_bf16<<<gq, 256, 0, stream>>>(nin, W + 1 * D_ * D_, bb + 1 * D_, kb, MQ, D_, D_);
    k_gemm_bf16<<<gq, 256, 0, stream>>>(nin, W + 2 * D_ * D_, bb + 2 * D_, vb, MQ, D_, D_);

    k_attn_window<<<(B_ * S2_ * H_) / 4, 256, 0, stream>>>(qb, kb, vb, cb, side);

    // out-projection over full S2 (3% waste, keeps M%128==0): cb @ W3 -> qb
    k_gemm_bf16<<<gq, 256, 0, stream>>>(cb, W + 3 * D_ * D_, bb + 3 * D_, qb, MQ, D_, D_);

    // hw input = proj[WIDTH:WIDTH+S] + rel window sum -> vb (B,S,D)
    k_rel_add<<<2048, 256, 0, stream>>>(qb, nin, wr, vb, side == 0 ? 0 : WIDTH_);

    dim3 gh((2 * D_) / 128, MH / 128);   // (8, 64)
    for (int l = 0; l < NHW_; ++l) {
      k_gemm_bf16<<<gh, 256, 0, stream>>>(vb, hW + (size_t)l * D_ * 2 * D_,
                                          hb + l * 2 * D_, hwp, MH, 2 * D_, D_);
      if (l < NHW_ - 1) {
        k_hw_combine<false><<<2048, 256, 0, stream>>>(vb, hwp, vb, nullptr, 0);
      } else {
        k_hw_combine<true><<<2048, 256, 0, stream>>>(vb, hwp, nullptr, out, side * D_);
      }
    }
  }
}

// Round 3
// 479.309 us; speedup vs baseline: 3.1666x; 3.1666x over previous
//
#include <hip/hip_runtime.h>

// SelfAttentiveLBLBiLM on MI355X — round 3: MFMA GEMM (m97 structure).
// fp32 I/O, bf16 internal. GEMM: C = A(M,K) @ B^T(N,K) via
// v_mfma_f32_16x16x32_bf16, 128x128 tile, BK=32, global_load_lds width-16
// staging, 4 waves x (4x4) 16x16 fragments, fp32 bias epilogue.
// Weights transposed+converted fp32->bf16 once per call (tiled LDS transpose).
// QKV fused into one N=1536 GEMM (q,k,v bias rows contiguous in (4,D)).

#define B_ 8
#define S_ 1024
#define D_ 512
#define H_ 8
#define DK_ 64
#define WIDTH_ 8
#define S2_ 1040
#define NHW_ 2

typedef short bf16x8 __attribute__((ext_vector_type(8)));
typedef float f32x4 __attribute__((ext_vector_type(4)));

__device__ __forceinline__ float us2f(unsigned short u) {
  union { unsigned int i; float f; } c; c.i = ((unsigned int)u) << 16; return c.f;
}
__device__ __forceinline__ unsigned short f2us(float f) {
  union { float f; unsigned int i; } c; c.f = f;
  unsigned int x = c.i;
  return (unsigned short)((x + 0x7fffu + ((x >> 16) & 1u)) >> 16);
}
__device__ __forceinline__ unsigned int pack2(float a, float b) {
  return (unsigned int)f2us(a) | ((unsigned int)f2us(b) << 16);
}
__device__ __forceinline__ void async16(const void* g, void* l) {
  __builtin_amdgcn_global_load_lds(
      (const __attribute__((address_space(1))) void*)g,
      (__attribute__((address_space(3))) void*)l, 16, 0, 0);
}

// ---------------------------------------------------------------------------
// Transpose + convert: src (rows x cols) fp32 -> dst (cols x rows) bf16.
// blockIdx.z selects a slice: src += z*rows*cols, dst += z*rows*cols.
// rows, cols multiples of 32. Block 256 = 32x8.
__global__ __launch_bounds__(256) void k_transpose_cvt(
    const float* __restrict__ src, unsigned short* __restrict__ dst,
    int rows, int cols)
{
  __shared__ float tile[32][33];
  const size_t sl = (size_t)blockIdx.z * rows * cols;
  src += sl; dst += sl;
  int c0 = blockIdx.x * 32, r0 = blockIdx.y * 32;
  int tx = threadIdx.x & 31, ty = threadIdx.x >> 5;   // ty 0..7
  #pragma unroll
  for (int i = 0; i < 4; ++i)
    tile[ty + i * 8][tx] = src[(size_t)(r0 + ty + i * 8) * cols + c0 + tx];
  __syncthreads();
  #pragma unroll
  for (int i = 0; i < 4; ++i)
    dst[(size_t)(c0 + ty + i * 8) * rows + r0 + tx] = f2us(tile[tx][ty + i * 8]);
}

// ---------------------------------------------------------------------------
// new_in = concat(left_pad, x, right_pad), (B,S2,D), fp32 -> bf16.
__global__ __launch_bounds__(256) void k_build_new_in(
    const float* __restrict__ x,
    const float* __restrict__ lpad,
    const float* __restrict__ rpad,
    unsigned short* __restrict__ nin)
{
  int gid = blockIdx.x * 256 + threadIdx.x;
  int c8 = (gid & 63) << 3;
  int row = gid >> 6;
  if (row >= B_ * S2_) return;
  int b = row / S2_;
  int t = row - b * S2_;
  const float* src;
  if (t < WIDTH_)            src = lpad + (size_t)t * D_ + c8;
  else if (t >= S_ + WIDTH_) src = rpad + (size_t)(t - S_ - WIDTH_) * D_ + c8;
  else                       src = x + ((size_t)b * S_ + (t - WIDTH_)) * D_ + c8;
  float4 a = *reinterpret_cast<const float4*>(src);
  float4 c = *reinterpret_cast<const float4*>(src + 4);
  uint4 o;
  o.x = pack2(a.x, a.y); o.y = pack2(a.z, a.w);
  o.z = pack2(c.x, c.y); o.w = pack2(c.z, c.w);
  *reinterpret_cast<uint4*>(nin + (size_t)row * D_ + c8) = o;
}

// ---------------------------------------------------------------------------
// MFMA GEMM: C(M,N) bf16 = A(M,K) bf16 @ BT(N,K)^T + bias(N) fp32.
// M%128==0, N%128==0, K%32==0. Block 256 (4 waves), tile 128x128, BK=32.
__global__ __launch_bounds__(256) void k_gemm_mfma(
    const unsigned short* __restrict__ A,
    const unsigned short* __restrict__ BT,
    const float* __restrict__ bias,
    unsigned short* __restrict__ C,
    int M, int N, int K)
{
  __shared__ unsigned short As[128 * 32];   // row-major [row][k], 8 KB
  __shared__ unsigned short Bs[128 * 32];

  const int tid = threadIdx.x;
  const int w = tid >> 6;          // wave 0..3
  const int l = tid & 63;
  const int bm = blockIdx.y * 128;
  const int bn = blockIdx.x * 128;
  const int wrow = (w >> 1) * 64;  // wave's 64x64 quadrant
  const int wcol = (w & 1) * 64;

  // staging: lane covers row w*16 + (l>>2) (+64 for 2nd inst), k-chunk (l&3)*8
  const int srow = w * 16 + (l >> 2);
  const int sk = (l & 3) * 8;
  const unsigned short* Ap = A + (size_t)(bm + srow) * K + sk;
  const unsigned short* Bp = BT + (size_t)(bn + srow) * K + sk;
  unsigned short* lA0 = &As[w * 512];
  unsigned short* lA1 = &As[2048 + w * 512];
  unsigned short* lB0 = &Bs[w * 512];
  unsigned short* lB1 = &Bs[2048 + w * 512];
  const size_t K64 = (size_t)64 * K;

  // fragment read offsets
  const int fl = l & 15;
  const int fk = (l >> 4) * 8;

  f32x4 acc[4][4];
  #pragma unroll
  for (int mi = 0; mi < 4; ++mi)
    #pragma unroll
    for (int ni = 0; ni < 4; ++ni) acc[mi][ni] = (f32x4){0.f, 0.f, 0.f, 0.f};

  for (int k0 = 0; k0 < K; k0 += 32) {
    async16(Ap + k0, lA0);
    async16(Ap + K64 + k0, lA1);
    async16(Bp + k0, lB0);
    async16(Bp + K64 + k0, lB1);
    __syncthreads();

    bf16x8 af[4], bf[4];
    #pragma unroll
    for (int mi = 0; mi < 4; ++mi)
      af[mi] = *reinterpret_cast<const bf16x8*>(&As[(wrow + mi * 16 + fl) * 32 + fk]);
    #pragma unroll
    for (int ni = 0; ni < 4; ++ni)
      bf[ni] = *reinterpret_cast<const bf16x8*>(&Bs[(wcol + ni * 16 + fl) * 32 + fk]);
    #pragma unroll
    for (int mi = 0; mi < 4; ++mi)
      #pragma unroll
      for (int ni = 0; ni < 4; ++ni)
        acc[mi][ni] = __builtin_amdgcn_mfma_f32_16x16x32_bf16(
            af[mi], bf[ni], acc[mi][ni], 0, 0, 0);
    __syncthreads();
  }

  // epilogue: C/D layout col = l&15, row = (l>>4)*4 + r
  float bv[4];
  #pragma unroll
  for (int ni = 0; ni < 4; ++ni) bv[ni] = bias[bn + wcol + ni * 16 + fl];

  const int rbase = (l >> 4) * 4;
  #pragma unroll
  for (int mi = 0; mi < 4; ++mi) {
    #pragma unroll
    for (int r = 0; r < 4; ++r) {
      int row = bm + wrow + mi * 16 + rbase + r;
      unsigned short* Cp = C + (size_t)row * N + bn + wcol + fl;
      #pragma unroll
      for (int ni = 0; ni < 4; ++ni)
        Cp[ni * 16] = f2us(acc[mi][ni][r] + bv[ni]);
    }
  }
}

// ---------------------------------------------------------------------------
// Windowed attention over fused qkv (ld=1536; q +0, k +512, v +1024).
// One wave per (b,i,h); lane = d within head (DK=64). scale 1/8.
__global__ __launch_bounds__(256) void k_attn_window(
    const unsigned short* __restrict__ qkv,
    unsigned short* __restrict__ ctx,
    int dir)
{
  int wid = (blockIdx.x * 256 + threadIdx.x) >> 6;
  int lane = threadIdx.x & 63;
  if (wid >= B_ * S2_ * H_) return;
  int h = wid & (H_ - 1);
  int i = (wid >> 3) % S2_;
  int b = wid / (S2_ * H_);

  const size_t rbase = (size_t)b * S2_ * 1536;
  const int col = h * DK_ + lane;
  float qd = us2f(qkv[rbase + (size_t)i * 1536 + col]);

  float sc[10];
  float mx = -1e30f;
  #pragma unroll
  for (int t = 0; t < 10; ++t) {
    int j = (dir == 0) ? (i - 9 + t) : (i + t);
    float s = -1e30f;
    if (j >= 0 && j < S2_) {
      float kd = us2f(qkv[rbase + (size_t)j * 1536 + 512 + col]);
      float p = qd * kd;
      #pragma unroll
      for (int off = 32; off > 0; off >>= 1) p += __shfl_xor(p, off);
      s = p * 0.125f;
    }
    sc[t] = s;
    mx = fmaxf(mx, s);
  }
  float denom = 0.f;
  #pragma unroll
  for (int t = 0; t < 10; ++t) {
    sc[t] = (sc[t] > -1e29f) ? __expf(sc[t] - mx) : 0.f;
    denom += sc[t];
  }
  float inv = 1.f / denom;
  float o = 0.f;
  #pragma unroll
  for (int t = 0; t < 10; ++t) {
    int j = (dir == 0) ? (i - 9 + t) : (i + t);
    if (j >= 0 && j < S2_ && sc[t] > 0.f) {
      float vd = us2f(qkv[rbase + (size_t)j * 1536 + 1024 + col]);
      o += sc[t] * vd;
    }
  }
  ctx[((size_t)b * S2_ + i) * D_ + col] = f2us(o * inv);
}

// ---------------------------------------------------------------------------
// hwx[b,s,:] = proj[b, WIDTH+s, :] + sum_{j=0..8} wrel[j]*nin[b, off+j+s, :]
__global__ __launch_bounds__(256) void k_rel_add(
    const unsigned short* __restrict__ proj,   // (B,S2,D) bf16
    const unsigned short* __restrict__ nin,    // (B,S2,D) bf16
    const float* __restrict__ wrel,            // 9 fp32
    unsigned short* __restrict__ hwx,          // (B,S,D) bf16
    int off)
{
  int gid = blockIdx.x * 256 + threadIdx.x;
  int c8 = (gid & 63) << 3;
  int row = gid >> 6;
  if (row >= B_ * S_) return;
  int b = row >> 10;
  int s = row & (S_ - 1);

  float acc[8];
  uint4 p4 = *reinterpret_cast<const uint4*>(
      proj + ((size_t)b * S2_ + WIDTH_ + s) * D_ + c8);
  unsigned int pw[4] = {p4.x, p4.y, p4.z, p4.w};
  #pragma unroll
  for (int c = 0; c < 4; ++c) {
    acc[2*c]     = us2f((unsigned short)(pw[c] & 0xffffu));
    acc[2*c + 1] = us2f((unsigned short)(pw[c] >> 16));
  }
  #pragma unroll
  for (int j = 0; j < 9; ++j) {
    float w = wrel[j];
    uint4 n4 = *reinterpret_cast<const uint4*>(
        nin + ((size_t)b * S2_ + off + j + s) * D_ + c8);
    unsigned int nw[4] = {n4.x, n4.y, n4.z, n4.w};
    #pragma unroll
    for (int c = 0; c < 4; ++c) {
      acc[2*c]     += w * us2f((unsigned short)(nw[c] & 0xffffu));
      acc[2*c + 1] += w * us2f((unsigned short)(nw[c] >> 16));
    }
  }
  uint4 o;
  o.x = pack2(acc[0], acc[1]); o.y = pack2(acc[2], acc[3]);
  o.z = pack2(acc[4], acc[5]); o.w = pack2(acc[6], acc[7]);
  *reinterpret_cast<uint4*>(hwx + (size_t)row * D_ + c8) = o;
}

// ---------------------------------------------------------------------------
// Highway gate: r = g*x + (1-g)*relu(nl). FP32OUT=true writes fp32 d_out
// (ld=2D, col offset coff); else bf16 (ld=D).
template <bool FP32OUT>
__global__ __launch_bounds__(256) void k_hw_combine(
    const unsigned short* __restrict__ x,      // (B*S, D) bf16
    const unsigned short* __restrict__ proj,   // (B*S, 2D) bf16
    unsigned short* __restrict__ outb,
    float* __restrict__ outf,
    int coff)
{
  int gid = blockIdx.x * 256 + threadIdx.x;
  int c8 = (gid & 63) << 3;
  int row = gid >> 6;
  if (row >= B_ * S_) return;

  uint4 xv = *reinterpret_cast<const uint4*>(x + (size_t)row * D_ + c8);
  uint4 nv = *reinterpret_cast<const uint4*>(proj + (size_t)row * (2 * D_) + c8);
  uint4 gv = *reinterpret_cast<const uint4*>(proj + (size_t)row * (2 * D_) + D_ + c8);
  unsigned int xw[4] = {xv.x, xv.y, xv.z, xv.w};
  unsigned int nw[4] = {nv.x, nv.y, nv.z, nv.w};
  unsigned int gw[4] = {gv.x, gv.y, gv.z, gv.w};
  float r[8];
  #pragma unroll
  for (int c = 0; c < 4; ++c) {
    #pragma unroll
    for (int hh = 0; hh < 2; ++hh) {
      unsigned short xu = hh ? (unsigned short)(xw[c] >> 16) : (unsigned short)(xw[c] & 0xffffu);
      unsigned short nu = hh ? (unsigned short)(nw[c] >> 16) : (unsigned short)(nw[c] & 0xffffu);
      unsigned short gu = hh ? (unsigned short)(gw[c] >> 16) : (unsigned short)(gw[c] & 0xffffu);
      float xf = us2f(xu);
      float nl = fmaxf(us2f(nu), 0.f);
      float g  = 1.f / (1.f + __expf(-us2f(gu)));
      r[2*c + hh] = g * xf + (1.f - g) * nl;
    }
  }
  if (FP32OUT) {
    float* Op = outf + (size_t)row * (2 * D_) + coff + c8;
    *reinterpret_cast<float4*>(Op)     = make_float4(r[0], r[1], r[2], r[3]);
    *reinterpret_cast<float4*>(Op + 4) = make_float4(r[4], r[5], r[6], r[7]);
  } else {
    uint4 o;
    o.x = pack2(r[0], r[1]); o.y = pack2(r[2], r[3]);
    o.z = pack2(r[4], r[5]); o.w = pack2(r[6], r[7]);
    *reinterpret_cast<uint4*>(outb + (size_t)row * D_ + c8) = o;
  }
}

// ---------------------------------------------------------------------------
extern "C" void kernel_launch(void* const* d_in, const int* in_sizes, int n_in,
                              void* d_out, int out_size, void* d_ws, size_t ws_size,
                              hipStream_t stream) {
  const float* x    = (const float*)d_in[0];
  const float* lW   = (const float*)d_in[1];
  const float* lb   = (const float*)d_in[2];
  const float* rW   = (const float*)d_in[3];
  const float* rb   = (const float*)d_in[4];
  const float* lpad = (const float*)d_in[5];
  const float* rpad = (const float*)d_in[6];
  const float* lw   = (const float*)d_in[7];
  const float* rw   = (const float*)d_in[8];
  const float* lhwW = (const float*)d_in[9];
  const float* lhwb = (const float*)d_in[10];
  const float* rhwW = (const float*)d_in[11];
  const float* rhwb = (const float*)d_in[12];
  float* out = (float*)d_out;
  unsigned short* ws = (unsigned short*)d_ws;

  const size_t NIN  = (size_t)B_ * S2_ * D_;        // 4,259,840
  const size_t NQKV = (size_t)B_ * S2_ * 1536;      // 12,779,520
  const size_t NHWP = (size_t)B_ * S_ * 2 * D_;     // 8,388,608
  const size_t NAW  = (size_t)4 * D_ * D_;          // 1,048,576 per side (qkv+proj T)
  const size_t NHW  = (size_t)NHW_ * D_ * 2 * D_;   // 1,048,576 per side

  unsigned short* nin  = ws;
  unsigned short* qkv  = nin + NIN;                 // aliased: proj@+0, hwx@+NIN
  unsigned short* proj = qkv;
  unsigned short* hwx  = qkv + NIN;
  unsigned short* cb   = qkv + NQKV;
  unsigned short* hwp  = cb + NIN;
  unsigned short* lWT  = hwp + NHWP;                // (1536+512) x 512
  unsigned short* rWT  = lWT + NAW;
  unsigned short* lhWT = rWT + NAW;                 // 2 x (1024 x 512)
  unsigned short* rhWT = lhWT + NHW;
  // total: 33,882,112 bf16 = 67.8 MB

  // transpose+convert weights: attn (4 slices 512x512/side), hw (2 slices 512x1024/side)
  {
    dim3 ga(16, 16, 4);
    k_transpose_cvt<<<ga, 256, 0, stream>>>(lW, lWT, D_, D_);
    k_transpose_cvt<<<ga, 256, 0, stream>>>(rW, rWT, D_, D_);
    dim3 gh(32, 16, 2);
    k_transpose_cvt<<<gh, 256, 0, stream>>>(lhwW, lhWT, D_, 2 * D_);
    k_transpose_cvt<<<gh, 256, 0, stream>>>(rhwW, rhWT, D_, 2 * D_);
  }

  k_build_new_in<<<2080, 256, 0, stream>>>(x, lpad, rpad, nin);

  const int MQ = B_ * S2_;   // 8320
  const int MH = B_ * S_;    // 8192

  for (int side = 0; side < 2; ++side) {
    const unsigned short* WT  = side ? rWT : lWT;
    const float* bb           = side ? rb : lb;
    const float* wr           = side ? rw : lw;
    const unsigned short* hWT = side ? rhWT : lhWT;
    const float* hb           = side ? rhwb : lhwb;

    // fused QKV: (8320 x 1536) = nin @ [Wq|Wk|Wv]; bias rows 0..2 contiguous
    dim3 gqkv(1536 / 128, MQ / 128);     // (12, 65)
    k_gemm_mfma<<<gqkv, 256, 0, stream>>>(nin, WT, bb, qkv, MQ, 1536, D_);

    k_attn_window<<<(B_ * S2_ * H_) / 4, 256, 0, stream>>>(qkv, cb, side);

    // out-projection: cb @ W3 -> proj (aliases qkv; qkv dead after attn)
    dim3 gp(D_ / 128, MQ / 128);         // (4, 65)
    k_gemm_mfma<<<gp, 256, 0, stream>>>(cb, WT + 3 * D_ * D_, bb + 3 * D_,
                                        proj, MQ, D_, D_);

    k_rel_add<<<2048, 256, 0, stream>>>(proj, nin, wr, hwx, side == 0 ? 0 : WIDTH_);

    dim3 gh((2 * D_) / 128, MH / 128);   // (8, 64)
    for (int l = 0; l < NHW_; ++l) {
      k_gemm_mfma<<<gh, 256, 0, stream>>>(hwx, hWT + (size_t)l * D_ * 2 * D_,
                                          hb + l * 2 * D_, hwp, MH, 2 * D_, D_);
      if (l < NHW_ - 1) {
        k_hw_combine<false><<<2048, 256, 0, stream>>>(hwx, hwp, hwx, nullptr, 0);
      } else {
        k_hw_combine<true><<<2048, 256, 0, stream>>>(hwx, hwp, nullptr, out, side * D_);
      }
    }
  }
}

// Round 4
// 368.094 us; speedup vs baseline: 4.1233x; 1.3021x over previous
//
#include <hip/hip_runtime.h>

// SelfAttentiveLBLBiLM on MI355X — round 4: attention rewrite.
// Round-3 profile: k_attn_window 83.7us x2 = 35% of total, VALUBusy 81%
// (60 full-wave shuffles + 21 scalar 2B loads per wave, 8 waves per (b,i)).
// Now: one wave per (b,i); lane owns 8 channels (uint4 bf16x8 loads); head =
// aligned 8-lane subgroup -> 3 shfl_xor per QK dot instead of 6 full-wave.
// GEMMs unchanged (MFMA 128x128, global_load_lds, m97 structure).

#define B_ 8
#define S_ 1024
#define D_ 512
#define H_ 8
#define DK_ 64
#define WIDTH_ 8
#define S2_ 1040
#define NHW_ 2

typedef short bf16x8 __attribute__((ext_vector_type(8)));
typedef float f32x4 __attribute__((ext_vector_type(4)));

__device__ __forceinline__ float us2f(unsigned short u) {
  union { unsigned int i; float f; } c; c.i = ((unsigned int)u) << 16; return c.f;
}
__device__ __forceinline__ unsigned short f2us(float f) {
  union { float f; unsigned int i; } c; c.f = f;
  unsigned int x = c.i;
  return (unsigned short)((x + 0x7fffu + ((x >> 16) & 1u)) >> 16);
}
__device__ __forceinline__ unsigned int pack2(float a, float b) {
  return (unsigned int)f2us(a) | ((unsigned int)f2us(b) << 16);
}
__device__ __forceinline__ void async16(const void* g, void* l) {
  __builtin_amdgcn_global_load_lds(
      (const __attribute__((address_space(1))) void*)g,
      (__attribute__((address_space(3))) void*)l, 16, 0, 0);
}
// unpack 8 bf16 (uint4) -> 8 fp32
__device__ __forceinline__ void unpack8(uint4 u, float* f) {
  unsigned int w[4] = {u.x, u.y, u.z, u.w};
  #pragma unroll
  for (int c = 0; c < 4; ++c) {
    union { unsigned int i; float g; } lo, hi;
    lo.i = w[c] << 16;
    hi.i = w[c] & 0xffff0000u;
    f[2 * c] = lo.g;
    f[2 * c + 1] = hi.g;
  }
}

// ---------------------------------------------------------------------------
// Transpose + convert: src (rows x cols) fp32 -> dst (cols x rows) bf16.
__global__ __launch_bounds__(256) void k_transpose_cvt(
    const float* __restrict__ src, unsigned short* __restrict__ dst,
    int rows, int cols)
{
  __shared__ float tile[32][33];
  const size_t sl = (size_t)blockIdx.z * rows * cols;
  src += sl; dst += sl;
  int c0 = blockIdx.x * 32, r0 = blockIdx.y * 32;
  int tx = threadIdx.x & 31, ty = threadIdx.x >> 5;
  #pragma unroll
  for (int i = 0; i < 4; ++i)
    tile[ty + i * 8][tx] = src[(size_t)(r0 + ty + i * 8) * cols + c0 + tx];
  __syncthreads();
  #pragma unroll
  for (int i = 0; i < 4; ++i)
    dst[(size_t)(c0 + ty + i * 8) * rows + r0 + tx] = f2us(tile[tx][ty + i * 8]);
}

// ---------------------------------------------------------------------------
// new_in = concat(left_pad, x, right_pad), (B,S2,D), fp32 -> bf16.
__global__ __launch_bounds__(256) void k_build_new_in(
    const float* __restrict__ x,
    const float* __restrict__ lpad,
    const float* __restrict__ rpad,
    unsigned short* __restrict__ nin)
{
  int gid = blockIdx.x * 256 + threadIdx.x;
  int c8 = (gid & 63) << 3;
  int row = gid >> 6;
  if (row >= B_ * S2_) return;
  int b = row / S2_;
  int t = row - b * S2_;
  const float* src;
  if (t < WIDTH_)            src = lpad + (size_t)t * D_ + c8;
  else if (t >= S_ + WIDTH_) src = rpad + (size_t)(t - S_ - WIDTH_) * D_ + c8;
  else                       src = x + ((size_t)b * S_ + (t - WIDTH_)) * D_ + c8;
  float4 a = *reinterpret_cast<const float4*>(src);
  float4 c = *reinterpret_cast<const float4*>(src + 4);
  uint4 o;
  o.x = pack2(a.x, a.y); o.y = pack2(a.z, a.w);
  o.z = pack2(c.x, c.y); o.w = pack2(c.z, c.w);
  *reinterpret_cast<uint4*>(nin + (size_t)row * D_ + c8) = o;
}

// ---------------------------------------------------------------------------
// MFMA GEMM: C(M,N) bf16 = A(M,K) bf16 @ BT(N,K)^T + bias(N) fp32.
__global__ __launch_bounds__(256) void k_gemm_mfma(
    const unsigned short* __restrict__ A,
    const unsigned short* __restrict__ BT,
    const float* __restrict__ bias,
    unsigned short* __restrict__ C,
    int M, int N, int K)
{
  __shared__ unsigned short As[128 * 32];
  __shared__ unsigned short Bs[128 * 32];

  const int tid = threadIdx.x;
  const int w = tid >> 6;
  const int l = tid & 63;
  const int bm = blockIdx.y * 128;
  const int bn = blockIdx.x * 128;
  const int wrow = (w >> 1) * 64;
  const int wcol = (w & 1) * 64;

  const int srow = w * 16 + (l >> 2);
  const int sk = (l & 3) * 8;
  const unsigned short* Ap = A + (size_t)(bm + srow) * K + sk;
  const unsigned short* Bp = BT + (size_t)(bn + srow) * K + sk;
  unsigned short* lA0 = &As[w * 512];
  unsigned short* lA1 = &As[2048 + w * 512];
  unsigned short* lB0 = &Bs[w * 512];
  unsigned short* lB1 = &Bs[2048 + w * 512];
  const size_t K64 = (size_t)64 * K;

  const int fl = l & 15;
  const int fk = (l >> 4) * 8;

  f32x4 acc[4][4];
  #pragma unroll
  for (int mi = 0; mi < 4; ++mi)
    #pragma unroll
    for (int ni = 0; ni < 4; ++ni) acc[mi][ni] = (f32x4){0.f, 0.f, 0.f, 0.f};

  for (int k0 = 0; k0 < K; k0 += 32) {
    async16(Ap + k0, lA0);
    async16(Ap + K64 + k0, lA1);
    async16(Bp + k0, lB0);
    async16(Bp + K64 + k0, lB1);
    __syncthreads();

    bf16x8 af[4], bfr[4];
    #pragma unroll
    for (int mi = 0; mi < 4; ++mi)
      af[mi] = *reinterpret_cast<const bf16x8*>(&As[(wrow + mi * 16 + fl) * 32 + fk]);
    #pragma unroll
    for (int ni = 0; ni < 4; ++ni)
      bfr[ni] = *reinterpret_cast<const bf16x8*>(&Bs[(wcol + ni * 16 + fl) * 32 + fk]);
    #pragma unroll
    for (int mi = 0; mi < 4; ++mi)
      #pragma unroll
      for (int ni = 0; ni < 4; ++ni)
        acc[mi][ni] = __builtin_amdgcn_mfma_f32_16x16x32_bf16(
            af[mi], bfr[ni], acc[mi][ni], 0, 0, 0);
    __syncthreads();
  }

  float bv[4];
  #pragma unroll
  for (int ni = 0; ni < 4; ++ni) bv[ni] = bias[bn + wcol + ni * 16 + fl];

  const int rbase = (l >> 4) * 4;
  #pragma unroll
  for (int mi = 0; mi < 4; ++mi) {
    #pragma unroll
    for (int r = 0; r < 4; ++r) {
      int row = bm + wrow + mi * 16 + rbase + r;
      unsigned short* Cp = C + (size_t)row * N + bn + wcol + fl;
      #pragma unroll
      for (int ni = 0; ni < 4; ++ni)
        Cp[ni * 16] = f2us(acc[mi][ni][r] + bv[ni]);
    }
  }
}

// ---------------------------------------------------------------------------
// Windowed attention, one wave per (b,i). Lane l owns channels l*8..l*8+7
// (uint4 bf16x8). Head h = l>>3 lives in aligned 8-lane subgroup: QK dot =
// 8 lane FMA + shfl_xor(1,2,4). qkv fused (ld 1536: q+0,k+512,v+1024).
__global__ __launch_bounds__(256) void k_attn_window(
    const unsigned short* __restrict__ qkv,
    unsigned short* __restrict__ ctx,
    int dir)
{
  int wid = (blockIdx.x * 256 + threadIdx.x) >> 6;   // b*S2 + i
  int lane = threadIdx.x & 63;
  if (wid >= B_ * S2_) return;
  int i = wid % S2_;
  int b = wid / S2_;

  const size_t base = (size_t)b * S2_ * 1536;
  const int c0 = lane * 8;

  float qf[8];
  unpack8(*reinterpret_cast<const uint4*>(qkv + base + (size_t)i * 1536 + c0), qf);

  float sc[10];
  float mx = -1e30f;
  #pragma unroll
  for (int t = 0; t < 10; ++t) {
    int j = (dir == 0) ? (i - 9 + t) : (i + t);
    float s = -1e30f;
    if (j >= 0 && j < S2_) {                 // wave-uniform branch
      float kf[8];
      unpack8(*reinterpret_cast<const uint4*>(
          qkv + base + (size_t)j * 1536 + 512 + c0), kf);
      float p = qf[0] * kf[0];
      #pragma unroll
      for (int e = 1; e < 8; ++e) p += qf[e] * kf[e];
      p += __shfl_xor(p, 1);
      p += __shfl_xor(p, 2);
      p += __shfl_xor(p, 4);                 // full head-dot in all 8 lanes
      s = p * 0.125f;
    }
    sc[t] = s;
    mx = fmaxf(mx, s);
  }

  float denom = 0.f;
  #pragma unroll
  for (int t = 0; t < 10; ++t) {
    sc[t] = (sc[t] > -1e29f) ? __expf(sc[t] - mx) : 0.f;
    denom += sc[t];
  }
  float inv = 1.f / denom;

  float acc[8] = {0.f, 0.f, 0.f, 0.f, 0.f, 0.f, 0.f, 0.f};
  #pragma unroll
  for (int t = 0; t < 10; ++t) {
    int j = (dir == 0) ? (i - 9 + t) : (i + t);
    if (j >= 0 && j < S2_) {
      float vf[8];
      unpack8(*reinterpret_cast<const uint4*>(
          qkv + base + (size_t)j * 1536 + 1024 + c0), vf);
      float p = sc[t];
      #pragma unroll
      for (int e = 0; e < 8; ++e) acc[e] += p * vf[e];
    }
  }

  uint4 o;
  o.x = pack2(acc[0] * inv, acc[1] * inv);
  o.y = pack2(acc[2] * inv, acc[3] * inv);
  o.z = pack2(acc[4] * inv, acc[5] * inv);
  o.w = pack2(acc[6] * inv, acc[7] * inv);
  *reinterpret_cast<uint4*>(ctx + ((size_t)b * S2_ + i) * D_ + c0) = o;
}

// ---------------------------------------------------------------------------
// hwx[b,s,:] = proj[b, WIDTH+s, :] + sum_{j=0..8} wrel[j]*nin[b, off+j+s, :]
__global__ __launch_bounds__(256) void k_rel_add(
    const unsigned short* __restrict__ proj,
    const unsigned short* __restrict__ nin,
    const float* __restrict__ wrel,
    unsigned short* __restrict__ hwx,
    int off)
{
  int gid = blockIdx.x * 256 + threadIdx.x;
  int c8 = (gid & 63) << 3;
  int row = gid >> 6;
  if (row >= B_ * S_) return;
  int b = row >> 10;
  int s = row & (S_ - 1);

  float acc[8];
  unpack8(*reinterpret_cast<const uint4*>(
      proj + ((size_t)b * S2_ + WIDTH_ + s) * D_ + c8), acc);
  #pragma unroll
  for (int j = 0; j < 9; ++j) {
    float w = wrel[j];
    float nf[8];
    unpack8(*reinterpret_cast<const uint4*>(
        nin + ((size_t)b * S2_ + off + j + s) * D_ + c8), nf);
    #pragma unroll
    for (int e = 0; e < 8; ++e) acc[e] += w * nf[e];
  }
  uint4 o;
  o.x = pack2(acc[0], acc[1]); o.y = pack2(acc[2], acc[3]);
  o.z = pack2(acc[4], acc[5]); o.w = pack2(acc[6], acc[7]);
  *reinterpret_cast<uint4*>(hwx + (size_t)row * D_ + c8) = o;
}

// ---------------------------------------------------------------------------
// Highway gate: r = g*x + (1-g)*relu(nl).
template <bool FP32OUT>
__global__ __launch_bounds__(256) void k_hw_combine(
    const unsigned short* __restrict__ x,
    const unsigned short* __restrict__ proj,
    unsigned short* __restrict__ outb,
    float* __restrict__ outf,
    int coff)
{
  int gid = blockIdx.x * 256 + threadIdx.x;
  int c8 = (gid & 63) << 3;
  int row = gid >> 6;
  if (row >= B_ * S_) return;

  float xf[8], nf[8], gf[8];
  unpack8(*reinterpret_cast<const uint4*>(x + (size_t)row * D_ + c8), xf);
  unpack8(*reinterpret_cast<const uint4*>(proj + (size_t)row * (2 * D_) + c8), nf);
  unpack8(*reinterpret_cast<const uint4*>(proj + (size_t)row * (2 * D_) + D_ + c8), gf);
  float r[8];
  #pragma unroll
  for (int e = 0; e < 8; ++e) {
    float nl = fmaxf(nf[e], 0.f);
    float g = 1.f / (1.f + __expf(-gf[e]));
    r[e] = g * xf[e] + (1.f - g) * nl;
  }
  if (FP32OUT) {
    float* Op = outf + (size_t)row * (2 * D_) + coff + c8;
    *reinterpret_cast<float4*>(Op)     = make_float4(r[0], r[1], r[2], r[3]);
    *reinterpret_cast<float4*>(Op + 4) = make_float4(r[4], r[5], r[6], r[7]);
  } else {
    uint4 o;
    o.x = pack2(r[0], r[1]); o.y = pack2(r[2], r[3]);
    o.z = pack2(r[4], r[5]); o.w = pack2(r[6], r[7]);
    *reinterpret_cast<uint4*>(outb + (size_t)row * D_ + c8) = o;
  }
}

// ---------------------------------------------------------------------------
extern "C" void kernel_launch(void* const* d_in, const int* in_sizes, int n_in,
                              void* d_out, int out_size, void* d_ws, size_t ws_size,
                              hipStream_t stream) {
  const float* x    = (const float*)d_in[0];
  const float* lW   = (const float*)d_in[1];
  const float* lb   = (const float*)d_in[2];
  const float* rW   = (const float*)d_in[3];
  const float* rb   = (const float*)d_in[4];
  const float* lpad = (const float*)d_in[5];
  const float* rpad = (const float*)d_in[6];
  const float* lw   = (const float*)d_in[7];
  const float* rw   = (const float*)d_in[8];
  const float* lhwW = (const float*)d_in[9];
  const float* lhwb = (const float*)d_in[10];
  const float* rhwW = (const float*)d_in[11];
  const float* rhwb = (const float*)d_in[12];
  float* out = (float*)d_out;
  unsigned short* ws = (unsigned short*)d_ws;

  const size_t NIN  = (size_t)B_ * S2_ * D_;
  const size_t NQKV = (size_t)B_ * S2_ * 1536;
  const size_t NHWP = (size_t)B_ * S_ * 2 * D_;
  const size_t NAW  = (size_t)4 * D_ * D_;
  const size_t NHW  = (size_t)NHW_ * D_ * 2 * D_;

  unsigned short* nin  = ws;
  unsigned short* qkv  = nin + NIN;
  unsigned short* proj = qkv;
  unsigned short* hwx  = qkv + NIN;
  unsigned short* cb   = qkv + NQKV;
  unsigned short* hwp  = cb + NIN;
  unsigned short* lWT  = hwp + NHWP;
  unsigned short* rWT  = lWT + NAW;
  unsigned short* lhWT = rWT + NAW;
  unsigned short* rhWT = lhWT + NHW;

  {
    dim3 ga(16, 16, 4);
    k_transpose_cvt<<<ga, 256, 0, stream>>>(lW, lWT, D_, D_);
    k_transpose_cvt<<<ga, 256, 0, stream>>>(rW, rWT, D_, D_);
    dim3 gh(32, 16, 2);
    k_transpose_cvt<<<gh, 256, 0, stream>>>(lhwW, lhWT, D_, 2 * D_);
    k_transpose_cvt<<<gh, 256, 0, stream>>>(rhwW, rhWT, D_, 2 * D_);
  }

  k_build_new_in<<<2080, 256, 0, stream>>>(x, lpad, rpad, nin);

  const int MQ = B_ * S2_;   // 8320
  const int MH = B_ * S_;    // 8192

  for (int side = 0; side < 2; ++side) {
    const unsigned short* WT  = side ? rWT : lWT;
    const float* bb           = side ? rb : lb;
    const float* wr           = side ? rw : lw;
    const unsigned short* hWT = side ? rhWT : lhWT;
    const float* hb           = side ? rhwb : lhwb;

    dim3 gqkv(1536 / 128, MQ / 128);
    k_gemm_mfma<<<gqkv, 256, 0, stream>>>(nin, WT, bb, qkv, MQ, 1536, D_);

    k_attn_window<<<(B_ * S2_ + 3) / 4, 256, 0, stream>>>(qkv, cb, side);

    dim3 gp(D_ / 128, MQ / 128);
    k_gemm_mfma<<<gp, 256, 0, stream>>>(cb, WT + 3 * D_ * D_, bb + 3 * D_,
                                        proj, MQ, D_, D_);

    k_rel_add<<<2048, 256, 0, stream>>>(proj, nin, wr, hwx, side == 0 ? 0 : WIDTH_);

    dim3 gh((2 * D_) / 128, MH / 128);
    for (int l = 0; l < NHW_; ++l) {
      k_gemm_mfma<<<gh, 256, 0, stream>>>(hwx, hWT + (size_t)l * D_ * 2 * D_,
                                          hb + l * 2 * D_, hwp, MH, 2 * D_, D_);
      if (l < NHW_ - 1) {
        k_hw_combine<false><<<2048, 256, 0, stream>>>(hwx, hwp, hwx, nullptr, 0);
      } else {
        k_hw_combine<true><<<2048, 256, 0, stream>>>(hwx, hwp, nullptr, out, side * D_);
      }
    }
  }
}

// Round 5
// 295.546 us; speedup vs baseline: 5.1355x; 1.2455x over previous
//
#include <hip/hip_runtime.h>

// SelfAttentiveLBLBiLM on MI355X — round 5: epilogue fusion + side batching.
// r4 post-mortem: ~95us of dispatch gaps (21 dispatches) + 4 combine kernels
// that only re-read the proj buffer. Now:
//  - highway gate fused into highway GEMM epilogue via column-interleaved
//    permuted weights (16-col groups [nl|gate|nl|gate...]) -> no proj buffer
//  - both sides batched via blockIdx.z (proj gemm, rel_add, hw gemm)
//  - QKV for both sides fused into one N=3072 GEMM; attention 1 dispatch
//  => 13 dispatches total.

#define B_ 8
#define S_ 1024
#define D_ 512
#define H_ 8
#define DK_ 64
#define WIDTH_ 8
#define S2_ 1040
#define NHW_ 2

typedef short bf16x8 __attribute__((ext_vector_type(8)));
typedef float f32x4 __attribute__((ext_vector_type(4)));

__device__ __forceinline__ float us2f(unsigned short u) {
  union { unsigned int i; float f; } c; c.i = ((unsigned int)u) << 16; return c.f;
}
__device__ __forceinline__ unsigned short f2us(float f) {
  union { float f; unsigned int i; } c; c.f = f;
  unsigned int x = c.i;
  return (unsigned short)((x + 0x7fffu + ((x >> 16) & 1u)) >> 16);
}
__device__ __forceinline__ unsigned int pack2(float a, float b) {
  return (unsigned int)f2us(a) | ((unsigned int)f2us(b) << 16);
}
__device__ __forceinline__ void async16(const void* g, void* l) {
  __builtin_amdgcn_global_load_lds(
      (const __attribute__((address_space(1))) void*)g,
      (__attribute__((address_space(3))) void*)l, 16, 0, 0);
}
__device__ __forceinline__ void unpack8(uint4 u, float* f) {
  unsigned int w[4] = {u.x, u.y, u.z, u.w};
  #pragma unroll
  for (int c = 0; c < 4; ++c) {
    union { unsigned int i; float g; } lo, hi;
    lo.i = w[c] << 16;
    hi.i = w[c] & 0xffff0000u;
    f[2 * c] = lo.g;
    f[2 * c + 1] = hi.g;
  }
}

// ---------------------------------------------------------------------------
// Transpose + convert: src (rows x cols) fp32 -> dst (cols x rows) bf16.
// blockIdx.z slice: src += z*rows*cols, dst += z*rows*cols.
__global__ __launch_bounds__(256) void k_transpose_cvt(
    const float* __restrict__ src, unsigned short* __restrict__ dst,
    int rows, int cols)
{
  __shared__ float tile[32][33];
  const size_t sl = (size_t)blockIdx.z * rows * cols;
  src += sl; dst += sl;
  int c0 = blockIdx.x * 32, r0 = blockIdx.y * 32;
  int tx = threadIdx.x & 31, ty = threadIdx.x >> 5;
  #pragma unroll
  for (int i = 0; i < 4; ++i)
    tile[ty + i * 8][tx] = src[(size_t)(r0 + ty + i * 8) * cols + c0 + tx];
  __syncthreads();
  #pragma unroll
  for (int i = 0; i < 4; ++i)
    dst[(size_t)(c0 + ty + i * 8) * rows + r0 + tx] = f2us(tile[tx][ty + i * 8]);
}

// ---------------------------------------------------------------------------
// Highway-weight transpose with column-interleave permutation.
// src: (512 x 1024) fp32 per layer slice (z). dst rows permuted:
// orig col c -> row q = (2*((c&511)>>4) + (c>=512))*16 + (c&15), ld 512.
__global__ __launch_bounds__(256) void k_transpose_hw(
    const float* __restrict__ src, unsigned short* __restrict__ dst)
{
  __shared__ float tile[32][33];
  src += (size_t)blockIdx.z * 512 * 1024;
  dst += (size_t)blockIdx.z * 1024 * 512;
  int c0 = blockIdx.x * 32, r0 = blockIdx.y * 32;
  int tx = threadIdx.x & 31, ty = threadIdx.x >> 5;
  #pragma unroll
  for (int i = 0; i < 4; ++i)
    tile[ty + i * 8][tx] = src[(size_t)(r0 + ty + i * 8) * 1024 + c0 + tx];
  __syncthreads();
  #pragma unroll
  for (int i = 0; i < 4; ++i) {
    int c = c0 + ty + i * 8;
    int q = (2 * ((c & 511) >> 4) + (c >= 512 ? 1 : 0)) * 16 + (c & 15);
    dst[(size_t)q * 512 + r0 + tx] = f2us(tile[tx][ty + i * 8]);
  }
}

// ---------------------------------------------------------------------------
// qkv bias concat: qb[0:1536)=lb, [1536:3072)=rb (fp32).
__global__ __launch_bounds__(256) void k_cat_bias(
    const float* __restrict__ lb, const float* __restrict__ rb,
    float* __restrict__ qb)
{
  int t = blockIdx.x * 256 + threadIdx.x;
  if (t < 1536) qb[t] = lb[t];
  else if (t < 3072) qb[t] = rb[t - 1536];
}

// ---------------------------------------------------------------------------
// new_in = concat(left_pad, x, right_pad), (B,S2,D), fp32 -> bf16.
__global__ __launch_bounds__(256) void k_build_new_in(
    const float* __restrict__ x,
    const float* __restrict__ lpad,
    const float* __restrict__ rpad,
    unsigned short* __restrict__ nin)
{
  int gid = blockIdx.x * 256 + threadIdx.x;
  int c8 = (gid & 63) << 3;
  int row = gid >> 6;
  if (row >= B_ * S2_) return;
  int b = row / S2_;
  int t = row - b * S2_;
  const float* src;
  if (t < WIDTH_)            src = lpad + (size_t)t * D_ + c8;
  else if (t >= S_ + WIDTH_) src = rpad + (size_t)(t - S_ - WIDTH_) * D_ + c8;
  else                       src = x + ((size_t)b * S_ + (t - WIDTH_)) * D_ + c8;
  float4 a = *reinterpret_cast<const float4*>(src);
  float4 c = *reinterpret_cast<const float4*>(src + 4);
  uint4 o;
  o.x = pack2(a.x, a.y); o.y = pack2(a.z, a.w);
  o.z = pack2(c.x, c.y); o.w = pack2(c.z, c.w);
  *reinterpret_cast<uint4*>(nin + (size_t)row * D_ + c8) = o;
}

// ---------------------------------------------------------------------------
// MFMA GEMM (z-batched): C(M,N) = A(M,K) @ BT(N,K)^T + bias(N).
// z = blockIdx.z selects A/BT/C offset and bias pointer.
__global__ __launch_bounds__(256) void k_gemm_mfma(
    const unsigned short* __restrict__ A, size_t aStrZ,
    const unsigned short* __restrict__ BT, size_t bStrZ,
    const float* __restrict__ bias0, const float* __restrict__ bias1,
    unsigned short* __restrict__ C, size_t cStrZ,
    int M, int N, int K)
{
  __shared__ unsigned short As[128 * 32];
  __shared__ unsigned short Bs[128 * 32];

  const int z = blockIdx.z;
  A += (size_t)z * aStrZ; BT += (size_t)z * bStrZ; C += (size_t)z * cStrZ;
  const float* bias = z ? bias1 : bias0;

  const int tid = threadIdx.x;
  const int w = tid >> 6;
  const int l = tid & 63;
  const int bm = blockIdx.y * 128;
  const int bn = blockIdx.x * 128;
  const int wrow = (w >> 1) * 64;
  const int wcol = (w & 1) * 64;

  const int srow = w * 16 + (l >> 2);
  const int sk = (l & 3) * 8;
  const unsigned short* Ap = A + (size_t)(bm + srow) * K + sk;
  const unsigned short* Bp = BT + (size_t)(bn + srow) * K + sk;
  unsigned short* lA0 = &As[w * 512];
  unsigned short* lA1 = &As[2048 + w * 512];
  unsigned short* lB0 = &Bs[w * 512];
  unsigned short* lB1 = &Bs[2048 + w * 512];
  const size_t K64 = (size_t)64 * K;

  const int fl = l & 15;
  const int fk = (l >> 4) * 8;

  f32x4 acc[4][4];
  #pragma unroll
  for (int mi = 0; mi < 4; ++mi)
    #pragma unroll
    for (int ni = 0; ni < 4; ++ni) acc[mi][ni] = (f32x4){0.f, 0.f, 0.f, 0.f};

  for (int k0 = 0; k0 < K; k0 += 32) {
    async16(Ap + k0, lA0);
    async16(Ap + K64 + k0, lA1);
    async16(Bp + k0, lB0);
    async16(Bp + K64 + k0, lB1);
    __syncthreads();

    bf16x8 af[4], bfr[4];
    #pragma unroll
    for (int mi = 0; mi < 4; ++mi)
      af[mi] = *reinterpret_cast<const bf16x8*>(&As[(wrow + mi * 16 + fl) * 32 + fk]);
    #pragma unroll
    for (int ni = 0; ni < 4; ++ni)
      bfr[ni] = *reinterpret_cast<const bf16x8*>(&Bs[(wcol + ni * 16 + fl) * 32 + fk]);
    #pragma unroll
    for (int mi = 0; mi < 4; ++mi)
      #pragma unroll
      for (int ni = 0; ni < 4; ++ni)
        acc[mi][ni] = __builtin_amdgcn_mfma_f32_16x16x32_bf16(
            af[mi], bfr[ni], acc[mi][ni], 0, 0, 0);
    __syncthreads();
  }

  float bv[4];
  #pragma unroll
  for (int ni = 0; ni < 4; ++ni) bv[ni] = bias[bn + wcol + ni * 16 + fl];

  const int rbase = (l >> 4) * 4;
  #pragma unroll
  for (int mi = 0; mi < 4; ++mi) {
    #pragma unroll
    for (int r = 0; r < 4; ++r) {
      int row = bm + wrow + mi * 16 + rbase + r;
      unsigned short* Cp = C + (size_t)row * N + bn + wcol + fl;
      #pragma unroll
      for (int ni = 0; ni < 4; ++ni)
        Cp[ni * 16] = f2us(acc[mi][ni][r] + bv[ni]);
    }
  }
}

// ---------------------------------------------------------------------------
// Highway GEMM with fused gate epilogue. A/x = Xsrc + z*MS (8192x512 bf16).
// BT permuted-interleaved (1024x512): frag ni=2p -> nl cols, ni=2p+1 -> gate
// cols of the same 16 output channels. bias in ORIGINAL order (nl j, gate
// 512+j). FINAL: fp32 out (ld 1024, col off z*512); else bf16 (ld 512).
template <bool FINAL>
__global__ __launch_bounds__(256) void k_gemm_hw(
    const unsigned short* __restrict__ Xsrc,
    const unsigned short* __restrict__ BT, size_t bStrZ,
    const float* __restrict__ bias0, const float* __restrict__ bias1,
    unsigned short* __restrict__ Obf,
    float* __restrict__ Ofp)
{
  __shared__ unsigned short As[128 * 32];
  __shared__ unsigned short Bs[128 * 32];
  const int K = 512;
  const size_t MS = (size_t)B_ * S_ * D_;

  const int z = blockIdx.z;
  const unsigned short* A = Xsrc + (size_t)z * MS;
  BT += (size_t)z * bStrZ;
  const float* bias = z ? bias1 : bias0;

  const int tid = threadIdx.x;
  const int w = tid >> 6;
  const int l = tid & 63;
  const int bm = blockIdx.y * 128;
  const int bn = blockIdx.x * 128;
  const int wrow = (w >> 1) * 64;
  const int wcol = (w & 1) * 64;

  const int srow = w * 16 + (l >> 2);
  const int sk = (l & 3) * 8;
  const unsigned short* Ap = A + (size_t)(bm + srow) * K + sk;
  const unsigned short* Bp = BT + (size_t)(bn + srow) * K + sk;
  unsigned short* lA0 = &As[w * 512];
  unsigned short* lA1 = &As[2048 + w * 512];
  unsigned short* lB0 = &Bs[w * 512];
  unsigned short* lB1 = &Bs[2048 + w * 512];
  const size_t K64 = (size_t)64 * K;

  const int fl = l & 15;
  const int fk = (l >> 4) * 8;

  f32x4 acc[4][4];
  #pragma unroll
  for (int mi = 0; mi < 4; ++mi)
    #pragma unroll
    for (int ni = 0; ni < 4; ++ni) acc[mi][ni] = (f32x4){0.f, 0.f, 0.f, 0.f};

  for (int k0 = 0; k0 < K; k0 += 32) {
    async16(Ap + k0, lA0);
    async16(Ap + K64 + k0, lA1);
    async16(Bp + k0, lB0);
    async16(Bp + K64 + k0, lB1);
    __syncthreads();

    bf16x8 af[4], bfr[4];
    #pragma unroll
    for (int mi = 0; mi < 4; ++mi)
      af[mi] = *reinterpret_cast<const bf16x8*>(&As[(wrow + mi * 16 + fl) * 32 + fk]);
    #pragma unroll
    for (int ni = 0; ni < 4; ++ni)
      bfr[ni] = *reinterpret_cast<const bf16x8*>(&Bs[(wcol + ni * 16 + fl) * 32 + fk]);
    #pragma unroll
    for (int mi = 0; mi < 4; ++mi)
      #pragma unroll
      for (int ni = 0; ni < 4; ++ni)
        acc[mi][ni] = __builtin_amdgcn_mfma_f32_16x16x32_bf16(
            af[mi], bfr[ni], acc[mi][ni], 0, 0, 0);
    __syncthreads();
  }

  // epilogue: outcol = (bn+wcol)/2 + p*16 + fl (512 output channels)
  const int ocb = ((bn + wcol) >> 1) + fl;
  float bnl[2], bg[2];
  #pragma unroll
  for (int p = 0; p < 2; ++p) {
    bnl[p] = bias[ocb + p * 16];
    bg[p]  = bias[512 + ocb + p * 16];
  }

  const int rbase = (l >> 4) * 4;
  #pragma unroll
  for (int mi = 0; mi < 4; ++mi) {
    #pragma unroll
    for (int r = 0; r < 4; ++r) {
      int row = bm + wrow + mi * 16 + rbase + r;
      #pragma unroll
      for (int p = 0; p < 2; ++p) {
        int oc = ocb + p * 16;
        float nl = fmaxf(acc[mi][2 * p][r] + bnl[p], 0.f);
        float g  = 1.f / (1.f + __expf(-(acc[mi][2 * p + 1][r] + bg[p])));
        float xv = us2f(A[(size_t)row * 512 + oc]);
        float res = g * xv + (1.f - g) * nl;
        if (FINAL) Ofp[(size_t)row * 1024 + z * 512 + oc] = res;
        else       Obf[(size_t)z * MS + (size_t)row * 512 + oc] = f2us(res);
      }
    }
  }
}

// ---------------------------------------------------------------------------
// Windowed attention, both sides in one dispatch. Wave = (side, b, i).
// qkv ld 3072: side*1536 + {q:0, k:512, v:1024}. Lane owns 8 channels.
__global__ __launch_bounds__(256) void k_attn_window(
    const unsigned short* __restrict__ qkv,
    unsigned short* __restrict__ ctx)
{
  int wid = (blockIdx.x * 256 + threadIdx.x) >> 6;
  int lane = threadIdx.x & 63;
  int dir = 0;
  if (wid >= B_ * S2_) { dir = 1; wid -= B_ * S2_; }
  int i = wid % S2_;
  int b = wid / S2_;

  const size_t base = (size_t)b * S2_ * 3072 + dir * 1536;
  const int c0 = lane * 8;

  float qf[8];
  unpack8(*reinterpret_cast<const uint4*>(qkv + base + (size_t)i * 3072 + c0), qf);

  float sc[10];
  float mx = -1e30f;
  #pragma unroll
  for (int t = 0; t < 10; ++t) {
    int j = (dir == 0) ? (i - 9 + t) : (i + t);
    float s = -1e30f;
    if (j >= 0 && j < S2_) {
      float kf[8];
      unpack8(*reinterpret_cast<const uint4*>(
          qkv + base + (size_t)j * 3072 + 512 + c0), kf);
      float p = qf[0] * kf[0];
      #pragma unroll
      for (int e = 1; e < 8; ++e) p += qf[e] * kf[e];
      p += __shfl_xor(p, 1);
      p += __shfl_xor(p, 2);
      p += __shfl_xor(p, 4);
      s = p * 0.125f;
    }
    sc[t] = s;
    mx = fmaxf(mx, s);
  }

  float denom = 0.f;
  #pragma unroll
  for (int t = 0; t < 10; ++t) {
    sc[t] = (sc[t] > -1e29f) ? __expf(sc[t] - mx) : 0.f;
    denom += sc[t];
  }
  float inv = 1.f / denom;

  float acc[8] = {0.f, 0.f, 0.f, 0.f, 0.f, 0.f, 0.f, 0.f};
  #pragma unroll
  for (int t = 0; t < 10; ++t) {
    int j = (dir == 0) ? (i - 9 + t) : (i + t);
    if (j >= 0 && j < S2_) {
      float vf[8];
      unpack8(*reinterpret_cast<const uint4*>(
          qkv + base + (size_t)j * 3072 + 1024 + c0), vf);
      float p = sc[t];
      #pragma unroll
      for (int e = 0; e < 8; ++e) acc[e] += p * vf[e];
    }
  }

  uint4 o;
  o.x = pack2(acc[0] * inv, acc[1] * inv);
  o.y = pack2(acc[2] * inv, acc[3] * inv);
  o.z = pack2(acc[4] * inv, acc[5] * inv);
  o.w = pack2(acc[6] * inv, acc[7] * inv);
  *reinterpret_cast<uint4*>(
      ctx + ((size_t)dir * B_ * S2_ + (size_t)b * S2_ + i) * D_ + c0) = o;
}

// ---------------------------------------------------------------------------
// rel add, z-batched over side (blockIdx.y):
// hwx[z][b,s,:] = proj[z][b, WIDTH+s, :] + sum_j wrel_z[j]*nin[b, z*W+j+s, :]
__global__ __launch_bounds__(256) void k_rel_add(
    const unsigned short* __restrict__ proj,   // (2,B,S2,D) bf16
    const unsigned short* __restrict__ nin,    // (B,S2,D) bf16
    const float* __restrict__ wrel0,
    const float* __restrict__ wrel1,
    unsigned short* __restrict__ hwx)          // (2,B,S,D) bf16
{
  int z = blockIdx.y;
  const float* wrel = z ? wrel1 : wrel0;
  int off = z * WIDTH_;
  proj += (size_t)z * B_ * S2_ * D_;
  hwx  += (size_t)z * B_ * S_ * D_;

  int gid = blockIdx.x * 256 + threadIdx.x;
  int c8 = (gid & 63) << 3;
  int row = gid >> 6;
  if (row >= B_ * S_) return;
  int b = row >> 10;
  int s = row & (S_ - 1);

  float acc[8];
  unpack8(*reinterpret_cast<const uint4*>(
      proj + ((size_t)b * S2_ + WIDTH_ + s) * D_ + c8), acc);
  #pragma unroll
  for (int j = 0; j < 9; ++j) {
    float w = wrel[j];
    float nf[8];
    unpack8(*reinterpret_cast<const uint4*>(
        nin + ((size_t)b * S2_ + off + j + s) * D_ + c8), nf);
    #pragma unroll
    for (int e = 0; e < 8; ++e) acc[e] += w * nf[e];
  }
  uint4 o;
  o.x = pack2(acc[0], acc[1]); o.y = pack2(acc[2], acc[3]);
  o.z = pack2(acc[4], acc[5]); o.w = pack2(acc[6], acc[7]);
  *reinterpret_cast<uint4*>(hwx + (size_t)row * D_ + c8) = o;
}

// ---------------------------------------------------------------------------
extern "C" void kernel_launch(void* const* d_in, const int* in_sizes, int n_in,
                              void* d_out, int out_size, void* d_ws, size_t ws_size,
                              hipStream_t stream) {
  const float* x    = (const float*)d_in[0];
  const float* lW   = (const float*)d_in[1];
  const float* lb   = (const float*)d_in[2];
  const float* rW   = (const float*)d_in[3];
  const float* rb   = (const float*)d_in[4];
  const float* lpad = (const float*)d_in[5];
  const float* rpad = (const float*)d_in[6];
  const float* lw   = (const float*)d_in[7];
  const float* rw   = (const float*)d_in[8];
  const float* lhwW = (const float*)d_in[9];
  const float* lhwb = (const float*)d_in[10];
  const float* rhwW = (const float*)d_in[11];
  const float* rhwb = (const float*)d_in[12];
  float* out = (float*)d_out;
  unsigned short* ws = (unsigned short*)d_ws;

  const size_t NIN   = (size_t)B_ * S2_ * D_;       // 4,259,840
  const size_t NQKV  = (size_t)B_ * S2_ * 3072;     // 25,559,040
  const size_t MS    = (size_t)B_ * S_ * D_;        // 4,194,304
  const size_t DD    = (size_t)D_ * D_;             // 262,144
  const size_t LHW   = (size_t)1024 * 512;          // 524,288 per (side,layer)

  unsigned short* nin   = ws;
  unsigned short* qkv   = nin + NIN;
  unsigned short* proj  = qkv;                      // aliases qkv (dead after attn)
  unsigned short* cb    = qkv + NQKV;               // (2,B,S2,D)
  unsigned short* hwx   = cb + 2 * NIN;             // (2,B,S,D)
  unsigned short* hwy   = hwx + 2 * MS;             // (2,B,S,D)
  unsigned short* WTall = hwy + 2 * MS;             // (3072,512)
  unsigned short* WTp   = WTall + 6 * DD;           // (2,512,512)
  unsigned short* hWT   = WTp + 2 * DD;             // (2 sides,2 layers,1024,512)
  float* qkvbias        = (float*)(hWT + 4 * LHW);  // 3072 fp32
  // total ≈ 119 MB of d_ws (ws is ≥256 MB per fill WRITE_SIZE)

  // --- weight prep (6 small dispatches) ---
  {
    dim3 g(16, 16, 3);
    k_transpose_cvt<<<g, 256, 0, stream>>>(lW, WTall, D_, D_);
    k_transpose_cvt<<<g, 256, 0, stream>>>(rW, WTall + 3 * DD, D_, D_);
    dim3 gp(16, 16, 1);
    k_transpose_cvt<<<gp, 256, 0, stream>>>(lW + 3 * DD, WTp, D_, D_);
    k_transpose_cvt<<<gp, 256, 0, stream>>>(rW + 3 * DD, WTp + DD, D_, D_);
    dim3 gh(32, 16, 2);
    k_transpose_hw<<<gh, 256, 0, stream>>>(lhwW, hWT);
    k_transpose_hw<<<gh, 256, 0, stream>>>(rhwW, hWT + 2 * LHW);
  }
  k_cat_bias<<<12, 256, 0, stream>>>(lb, rb, qkvbias);
  k_build_new_in<<<2080, 256, 0, stream>>>(x, lpad, rpad, nin);

  const int MQ = B_ * S2_;   // 8320

  // --- fused QKV both sides: (8320 x 3072) ---
  {
    dim3 g(3072 / 128, MQ / 128, 1);   // (24, 65)
    k_gemm_mfma<<<g, 256, 0, stream>>>(nin, 0, WTall, 0, qkvbias, qkvbias,
                                       qkv, 0, MQ, 3072, D_);
  }

  // --- attention, both sides ---
  k_attn_window<<<(2 * B_ * S2_) / 4, 256, 0, stream>>>(qkv, cb);

  // --- out-projection, z-batched over side: cb[z] @ Wp[z] -> proj[z] ---
  {
    dim3 g(D_ / 128, MQ / 128, 2);     // (4, 65, 2)
    k_gemm_mfma<<<g, 256, 0, stream>>>(cb, NIN, WTp, DD, lb + 3 * D_, rb + 3 * D_,
                                       proj, NIN, MQ, D_, D_);
  }

  // --- rel add, z-batched ---
  {
    dim3 g(2048, 2);
    k_rel_add<<<g, 256, 0, stream>>>(proj, nin, lw, rw, hwx);
  }

  // --- highway layers: gemm + fused gate, z-batched over side ---
  {
    dim3 g(1024 / 128, (B_ * S_) / 128, 2);   // (8, 64, 2)
    k_gemm_hw<false><<<g, 256, 0, stream>>>(hwx, hWT, 2 * LHW,
                                            lhwb, rhwb, hwy, nullptr);
    k_gemm_hw<true><<<g, 256, 0, stream>>>(hwy, hWT + LHW, 2 * LHW,
                                           lhwb + 1024, rhwb + 1024,
                                           nullptr, out);
  }
}

// Round 6
// 268.910 us; speedup vs baseline: 5.6441x; 1.0991x over previous
//
#include <hip/hip_runtime.h>

// SelfAttentiveLBLBiLM on MI355X — round 6: GEMM BK=64 + XOR-swizzled LDS,
// prep dispatches merged.
// r5 post-mortem: QKV GEMM 477 TF (MfmaUtil 18.7%), 3.2e6 LDS bank-conflict
// cycles, 13 dispatches (8 prep). Now:
//  - BK=64 (8 K-iters, half the barrier drains), LDS 2x16KB
//  - k-chunk XOR swizzle: physical chunk = logical ^ (row&7); global source
//    address absorbs the swizzle so global_load_lds lane-contiguity holds;
//    fragment reads spread over all 32 banks (2-way = free)
//  - prep: 3 dispatches (z=8 attn transpose, z=4 hw transpose, build+bias)
//  => 9 dispatches total.

#define B_ 8
#define S_ 1024
#define D_ 512
#define H_ 8
#define DK_ 64
#define WIDTH_ 8
#define S2_ 1040
#define NHW_ 2

typedef short bf16x8 __attribute__((ext_vector_type(8)));
typedef float f32x4 __attribute__((ext_vector_type(4)));

__device__ __forceinline__ float us2f(unsigned short u) {
  union { unsigned int i; float f; } c; c.i = ((unsigned int)u) << 16; return c.f;
}
__device__ __forceinline__ unsigned short f2us(float f) {
  union { float f; unsigned int i; } c; c.f = f;
  unsigned int x = c.i;
  return (unsigned short)((x + 0x7fffu + ((x >> 16) & 1u)) >> 16);
}
__device__ __forceinline__ unsigned int pack2(float a, float b) {
  return (unsigned int)f2us(a) | ((unsigned int)f2us(b) << 16);
}
__device__ __forceinline__ void async16(const void* g, void* l) {
  __builtin_amdgcn_global_load_lds(
      (const __attribute__((address_space(1))) void*)g,
      (__attribute__((address_space(3))) void*)l, 16, 0, 0);
}
__device__ __forceinline__ void unpack8(uint4 u, float* f) {
  unsigned int w[4] = {u.x, u.y, u.z, u.w};
  #pragma unroll
  for (int c = 0; c < 4; ++c) {
    union { unsigned int i; float g; } lo, hi;
    lo.i = w[c] << 16;
    hi.i = w[c] & 0xffff0000u;
    f[2 * c] = lo.g;
    f[2 * c + 1] = hi.g;
  }
}

// ---------------------------------------------------------------------------
// All 8 attention-weight transposes in one dispatch. z: side=z>>2, slice=z&3.
// slices 0..2 -> WTall[(side*3+slice)], slice 3 -> WTp[side]. 512x512 each.
__global__ __launch_bounds__(256) void k_transpose_attn(
    const float* __restrict__ lW, const float* __restrict__ rW,
    unsigned short* __restrict__ WTall, unsigned short* __restrict__ WTp)
{
  __shared__ float tile[32][33];
  const size_t DD = (size_t)D_ * D_;
  int z = blockIdx.z, side = z >> 2, slice = z & 3;
  const float* src = (side ? rW : lW) + (size_t)slice * DD;
  unsigned short* dst = (slice < 3) ? WTall + ((size_t)(side * 3 + slice)) * DD
                                    : WTp + (size_t)side * DD;
  int c0 = blockIdx.x * 32, r0 = blockIdx.y * 32;
  int tx = threadIdx.x & 31, ty = threadIdx.x >> 5;
  #pragma unroll
  for (int i = 0; i < 4; ++i)
    tile[ty + i * 8][tx] = src[(size_t)(r0 + ty + i * 8) * D_ + c0 + tx];
  __syncthreads();
  #pragma unroll
  for (int i = 0; i < 4; ++i)
    dst[(size_t)(c0 + ty + i * 8) * D_ + r0 + tx] = f2us(tile[tx][ty + i * 8]);
}

// ---------------------------------------------------------------------------
// Highway-weight transpose with column-interleave permutation, all 4
// (side,layer) slices in one dispatch. z: side=z>>1, layer=z&1.
// orig col c -> row q = (2*((c&511)>>4) + (c>=512))*16 + (c&15), ld 512.
__global__ __launch_bounds__(256) void k_transpose_hw(
    const float* __restrict__ lhwW, const float* __restrict__ rhwW,
    unsigned short* __restrict__ hWT)
{
  __shared__ float tile[32][33];
  int z = blockIdx.z, side = z >> 1, layer = z & 1;
  const float* src = (side ? rhwW : lhwW) + (size_t)layer * 512 * 1024;
  unsigned short* dst = hWT + (size_t)(side * 2 + layer) * 1024 * 512;
  int c0 = blockIdx.x * 32, r0 = blockIdx.y * 32;
  int tx = threadIdx.x & 31, ty = threadIdx.x >> 5;
  #pragma unroll
  for (int i = 0; i < 4; ++i)
    tile[ty + i * 8][tx] = src[(size_t)(r0 + ty + i * 8) * 1024 + c0 + tx];
  __syncthreads();
  #pragma unroll
  for (int i = 0; i < 4; ++i) {
    int c = c0 + ty + i * 8;
    int q = (2 * ((c & 511) >> 4) + (c >= 512 ? 1 : 0)) * 16 + (c & 15);
    dst[(size_t)q * 512 + r0 + tx] = f2us(tile[tx][ty + i * 8]);
  }
}

// ---------------------------------------------------------------------------
// new_in = concat(left_pad, x, right_pad), (B,S2,D), fp32 -> bf16.
// Tail blocks (gid >= B*S2*64) build the 3072-entry fused qkv bias.
__global__ __launch_bounds__(256) void k_build_new_in(
    const float* __restrict__ x,
    const float* __restrict__ lpad,
    const float* __restrict__ rpad,
    const float* __restrict__ lb,
    const float* __restrict__ rb,
    unsigned short* __restrict__ nin,
    float* __restrict__ qkvbias)
{
  int gid = blockIdx.x * 256 + threadIdx.x;
  const int NTH = B_ * S2_ * 64;     // 532,480
  if (gid >= NTH) {
    int t = gid - NTH;
    if (t < 1536) qkvbias[t] = lb[t];
    else if (t < 3072) qkvbias[t] = rb[t - 1536];
    return;
  }
  int c8 = (gid & 63) << 3;
  int row = gid >> 6;
  int b = row / S2_;
  int t = row - b * S2_;
  const float* src;
  if (t < WIDTH_)            src = lpad + (size_t)t * D_ + c8;
  else if (t >= S_ + WIDTH_) src = rpad + (size_t)(t - S_ - WIDTH_) * D_ + c8;
  else                       src = x + ((size_t)b * S_ + (t - WIDTH_)) * D_ + c8;
  float4 a = *reinterpret_cast<const float4*>(src);
  float4 c = *reinterpret_cast<const float4*>(src + 4);
  uint4 o;
  o.x = pack2(a.x, a.y); o.y = pack2(a.z, a.w);
  o.z = pack2(c.x, c.y); o.w = pack2(c.z, c.w);
  *reinterpret_cast<uint4*>(nin + (size_t)row * D_ + c8) = o;
}

// ---------------------------------------------------------------------------
// MFMA GEMM (z-batched): C(M,N) = A(M,K) @ BT(N,K)^T + bias(N).
// BK=64, XOR-swizzled LDS (chunk ^= row&7), tile 128x128, 4 waves.
__global__ __launch_bounds__(256) void k_gemm_mfma(
    const unsigned short* __restrict__ A, size_t aStrZ,
    const unsigned short* __restrict__ BT, size_t bStrZ,
    const float* __restrict__ bias0, const float* __restrict__ bias1,
    unsigned short* __restrict__ C, size_t cStrZ,
    int M, int N, int K)
{
  __shared__ unsigned short As[128 * 64];   // 16 KB, row-major [row][64]
  __shared__ unsigned short Bs[128 * 64];

  const int z = blockIdx.z;
  A += (size_t)z * aStrZ; BT += (size_t)z * bStrZ; C += (size_t)z * cStrZ;
  const float* bias = z ? bias1 : bias0;

  const int tid = threadIdx.x;
  const int w = tid >> 6;
  const int l = tid & 63;
  const int bm = blockIdx.y * 128;
  const int bn = blockIdx.x * 128;
  const int wrow = (w >> 1) * 64;
  const int wcol = (w & 1) * 64;

  // staging: round r covers rows r*32 + w*8 + (l>>3); lane chunk l&7 holds
  // global (logical) chunk (l&7)^(row&7); row&7 == (l>>3)&7.
  const int lr = l >> 3;                     // 0..7
  const int sk = (((l & 7) ^ lr) & 7) * 8;   // swizzled global k-chunk (elems)
  const unsigned short* Ap = A + (size_t)(bm + w * 8 + lr) * K + sk;
  const unsigned short* Bp = BT + (size_t)(bn + w * 8 + lr) * K + sk;
  unsigned short* lA = &As[w * 512];         // (w*8)*64
  unsigned short* lB = &Bs[w * 512];
  const size_t K32 = (size_t)32 * K;

  const int fl = l & 15;
  const int fq = l >> 4;                     // 0..3: k-subchunk within 32
  const int fx = fl & 7;                     // row swizzle key

  f32x4 acc[4][4];
  #pragma unroll
  for (int mi = 0; mi < 4; ++mi)
    #pragma unroll
    for (int ni = 0; ni < 4; ++ni) acc[mi][ni] = (f32x4){0.f, 0.f, 0.f, 0.f};

  for (int k0 = 0; k0 < K; k0 += 64) {
    #pragma unroll
    for (int r = 0; r < 4; ++r) {
      async16(Ap + k0 + r * K32, lA + r * 2048);
      async16(Bp + k0 + r * K32, lB + r * 2048);
    }
    __syncthreads();
    #pragma unroll
    for (int s = 0; s < 2; ++s) {
      bf16x8 af[4], bfr[4];
      #pragma unroll
      for (int mi = 0; mi < 4; ++mi) {
        int R = wrow + mi * 16 + fl;
        af[mi] = *reinterpret_cast<const bf16x8*>(
            &As[R * 64 + (((s * 4 + fq) ^ fx) * 8)]);
      }
      #pragma unroll
      for (int ni = 0; ni < 4; ++ni) {
        int R = wcol + ni * 16 + fl;
        bfr[ni] = *reinterpret_cast<const bf16x8*>(
            &Bs[R * 64 + (((s * 4 + fq) ^ fx) * 8)]);
      }
      #pragma unroll
      for (int mi = 0; mi < 4; ++mi)
        #pragma unroll
        for (int ni = 0; ni < 4; ++ni)
          acc[mi][ni] = __builtin_amdgcn_mfma_f32_16x16x32_bf16(
              af[mi], bfr[ni], acc[mi][ni], 0, 0, 0);
    }
    __syncthreads();
  }

  float bv[4];
  #pragma unroll
  for (int ni = 0; ni < 4; ++ni) bv[ni] = bias[bn + wcol + ni * 16 + fl];

  const int rbase = (l >> 4) * 4;
  #pragma unroll
  for (int mi = 0; mi < 4; ++mi) {
    #pragma unroll
    for (int r = 0; r < 4; ++r) {
      int row = bm + wrow + mi * 16 + rbase + r;
      unsigned short* Cp = C + (size_t)row * N + bn + wcol + fl;
      #pragma unroll
      for (int ni = 0; ni < 4; ++ni)
        Cp[ni * 16] = f2us(acc[mi][ni][r] + bv[ni]);
    }
  }
}

// ---------------------------------------------------------------------------
// Highway GEMM with fused gate epilogue. BK=64 swizzled, same as k_gemm_mfma.
// BT permuted-interleaved (1024x512): frag ni=2p -> nl, ni=2p+1 -> gate of the
// same 16 output channels. bias original order (nl j, gate 512+j).
template <bool FINAL>
__global__ __launch_bounds__(256) void k_gemm_hw(
    const unsigned short* __restrict__ Xsrc,
    const unsigned short* __restrict__ BT, size_t bStrZ,
    const float* __restrict__ bias0, const float* __restrict__ bias1,
    unsigned short* __restrict__ Obf,
    float* __restrict__ Ofp)
{
  __shared__ unsigned short As[128 * 64];
  __shared__ unsigned short Bs[128 * 64];
  const int K = 512;
  const size_t MS = (size_t)B_ * S_ * D_;

  const int z = blockIdx.z;
  const unsigned short* A = Xsrc + (size_t)z * MS;
  BT += (size_t)z * bStrZ;
  const float* bias = z ? bias1 : bias0;

  const int tid = threadIdx.x;
  const int w = tid >> 6;
  const int l = tid & 63;
  const int bm = blockIdx.y * 128;
  const int bn = blockIdx.x * 128;
  const int wrow = (w >> 1) * 64;
  const int wcol = (w & 1) * 64;

  const int lr = l >> 3;
  const int sk = (((l & 7) ^ lr) & 7) * 8;
  const unsigned short* Ap = A + (size_t)(bm + w * 8 + lr) * K + sk;
  const unsigned short* Bp = BT + (size_t)(bn + w * 8 + lr) * K + sk;
  unsigned short* lA = &As[w * 512];
  unsigned short* lB = &Bs[w * 512];
  const size_t K32 = (size_t)32 * K;

  const int fl = l & 15;
  const int fq = l >> 4;
  const int fx = fl & 7;

  f32x4 acc[4][4];
  #pragma unroll
  for (int mi = 0; mi < 4; ++mi)
    #pragma unroll
    for (int ni = 0; ni < 4; ++ni) acc[mi][ni] = (f32x4){0.f, 0.f, 0.f, 0.f};

  for (int k0 = 0; k0 < K; k0 += 64) {
    #pragma unroll
    for (int r = 0; r < 4; ++r) {
      async16(Ap + k0 + r * K32, lA + r * 2048);
      async16(Bp + k0 + r * K32, lB + r * 2048);
    }
    __syncthreads();
    #pragma unroll
    for (int s = 0; s < 2; ++s) {
      bf16x8 af[4], bfr[4];
      #pragma unroll
      for (int mi = 0; mi < 4; ++mi) {
        int R = wrow + mi * 16 + fl;
        af[mi] = *reinterpret_cast<const bf16x8*>(
            &As[R * 64 + (((s * 4 + fq) ^ fx) * 8)]);
      }
      #pragma unroll
      for (int ni = 0; ni < 4; ++ni) {
        int R = wcol + ni * 16 + fl;
        bfr[ni] = *reinterpret_cast<const bf16x8*>(
            &Bs[R * 64 + (((s * 4 + fq) ^ fx) * 8)]);
      }
      #pragma unroll
      for (int mi = 0; mi < 4; ++mi)
        #pragma unroll
        for (int ni = 0; ni < 4; ++ni)
          acc[mi][ni] = __builtin_amdgcn_mfma_f32_16x16x32_bf16(
              af[mi], bfr[ni], acc[mi][ni], 0, 0, 0);
    }
    __syncthreads();
  }

  const int ocb = ((bn + wcol) >> 1) + fl;
  float bnl[2], bg[2];
  #pragma unroll
  for (int p = 0; p < 2; ++p) {
    bnl[p] = bias[ocb + p * 16];
    bg[p]  = bias[512 + ocb + p * 16];
  }

  const int rbase = (l >> 4) * 4;
  #pragma unroll
  for (int mi = 0; mi < 4; ++mi) {
    #pragma unroll
    for (int r = 0; r < 4; ++r) {
      int row = bm + wrow + mi * 16 + rbase + r;
      #pragma unroll
      for (int p = 0; p < 2; ++p) {
        int oc = ocb + p * 16;
        float nl = fmaxf(acc[mi][2 * p][r] + bnl[p], 0.f);
        float g  = 1.f / (1.f + __expf(-(acc[mi][2 * p + 1][r] + bg[p])));
        float xv = us2f(A[(size_t)row * 512 + oc]);
        float res = g * xv + (1.f - g) * nl;
        if (FINAL) Ofp[(size_t)row * 1024 + z * 512 + oc] = res;
        else       Obf[(size_t)z * MS + (size_t)row * 512 + oc] = f2us(res);
      }
    }
  }
}

// ---------------------------------------------------------------------------
// Windowed attention, both sides in one dispatch. Wave = (side, b, i).
// qkv ld 3072: side*1536 + {q:0, k:512, v:1024}. Lane owns 8 channels.
__global__ __launch_bounds__(256) void k_attn_window(
    const unsigned short* __restrict__ qkv,
    unsigned short* __restrict__ ctx)
{
  int wid = (blockIdx.x * 256 + threadIdx.x) >> 6;
  int lane = threadIdx.x & 63;
  int dir = 0;
  if (wid >= B_ * S2_) { dir = 1; wid -= B_ * S2_; }
  int i = wid % S2_;
  int b = wid / S2_;

  const size_t base = (size_t)b * S2_ * 3072 + dir * 1536;
  const int c0 = lane * 8;

  float qf[8];
  unpack8(*reinterpret_cast<const uint4*>(qkv + base + (size_t)i * 3072 + c0), qf);

  float sc[10];
  float mx = -1e30f;
  #pragma unroll
  for (int t = 0; t < 10; ++t) {
    int j = (dir == 0) ? (i - 9 + t) : (i + t);
    float s = -1e30f;
    if (j >= 0 && j < S2_) {
      float kf[8];
      unpack8(*reinterpret_cast<const uint4*>(
          qkv + base + (size_t)j * 3072 + 512 + c0), kf);
      float p = qf[0] * kf[0];
      #pragma unroll
      for (int e = 1; e < 8; ++e) p += qf[e] * kf[e];
      p += __shfl_xor(p, 1);
      p += __shfl_xor(p, 2);
      p += __shfl_xor(p, 4);
      s = p * 0.125f;
    }
    sc[t] = s;
    mx = fmaxf(mx, s);
  }

  float denom = 0.f;
  #pragma unroll
  for (int t = 0; t < 10; ++t) {
    sc[t] = (sc[t] > -1e29f) ? __expf(sc[t] - mx) : 0.f;
    denom += sc[t];
  }
  float inv = 1.f / denom;

  float acc[8] = {0.f, 0.f, 0.f, 0.f, 0.f, 0.f, 0.f, 0.f};
  #pragma unroll
  for (int t = 0; t < 10; ++t) {
    int j = (dir == 0) ? (i - 9 + t) : (i + t);
    if (j >= 0 && j < S2_) {
      float vf[8];
      unpack8(*reinterpret_cast<const uint4*>(
          qkv + base + (size_t)j * 3072 + 1024 + c0), vf);
      float p = sc[t];
      #pragma unroll
      for (int e = 0; e < 8; ++e) acc[e] += p * vf[e];
    }
  }

  uint4 o;
  o.x = pack2(acc[0] * inv, acc[1] * inv);
  o.y = pack2(acc[2] * inv, acc[3] * inv);
  o.z = pack2(acc[4] * inv, acc[5] * inv);
  o.w = pack2(acc[6] * inv, acc[7] * inv);
  *reinterpret_cast<uint4*>(
      ctx + ((size_t)dir * B_ * S2_ + (size_t)b * S2_ + i) * D_ + c0) = o;
}

// ---------------------------------------------------------------------------
// rel add, z-batched over side (blockIdx.y).
__global__ __launch_bounds__(256) void k_rel_add(
    const unsigned short* __restrict__ proj,   // (2,B,S2,D) bf16
    const unsigned short* __restrict__ nin,    // (B,S2,D) bf16
    const float* __restrict__ wrel0,
    const float* __restrict__ wrel1,
    unsigned short* __restrict__ hwx)          // (2,B,S,D) bf16
{
  int z = blockIdx.y;
  const float* wrel = z ? wrel1 : wrel0;
  int off = z * WIDTH_;
  proj += (size_t)z * B_ * S2_ * D_;
  hwx  += (size_t)z * B_ * S_ * D_;

  int gid = blockIdx.x * 256 + threadIdx.x;
  int c8 = (gid & 63) << 3;
  int row = gid >> 6;
  if (row >= B_ * S_) return;
  int b = row >> 10;
  int s = row & (S_ - 1);

  float acc[8];
  unpack8(*reinterpret_cast<const uint4*>(
      proj + ((size_t)b * S2_ + WIDTH_ + s) * D_ + c8), acc);
  #pragma unroll
  for (int j = 0; j < 9; ++j) {
    float w = wrel[j];
    float nf[8];
    unpack8(*reinterpret_cast<const uint4*>(
        nin + ((size_t)b * S2_ + off + j + s) * D_ + c8), nf);
    #pragma unroll
    for (int e = 0; e < 8; ++e) acc[e] += w * nf[e];
  }
  uint4 o;
  o.x = pack2(acc[0], acc[1]); o.y = pack2(acc[2], acc[3]);
  o.z = pack2(acc[4], acc[5]); o.w = pack2(acc[6], acc[7]);
  *reinterpret_cast<uint4*>(hwx + (size_t)row * D_ + c8) = o;
}

// ---------------------------------------------------------------------------
extern "C" void kernel_launch(void* const* d_in, const int* in_sizes, int n_in,
                              void* d_out, int out_size, void* d_ws, size_t ws_size,
                              hipStream_t stream) {
  const float* x    = (const float*)d_in[0];
  const float* lW   = (const float*)d_in[1];
  const float* lb   = (const float*)d_in[2];
  const float* rW   = (const float*)d_in[3];
  const float* rb   = (const float*)d_in[4];
  const float* lpad = (const float*)d_in[5];
  const float* rpad = (const float*)d_in[6];
  const float* lw   = (const float*)d_in[7];
  const float* rw   = (const float*)d_in[8];
  const float* lhwW = (const float*)d_in[9];
  const float* lhwb = (const float*)d_in[10];
  const float* rhwW = (const float*)d_in[11];
  const float* rhwb = (const float*)d_in[12];
  float* out = (float*)d_out;
  unsigned short* ws = (unsigned short*)d_ws;

  const size_t NIN  = (size_t)B_ * S2_ * D_;       // 4,259,840
  const size_t NQKV = (size_t)B_ * S2_ * 3072;     // 25,559,040
  const size_t MS   = (size_t)B_ * S_ * D_;        // 4,194,304
  const size_t DD   = (size_t)D_ * D_;             // 262,144
  const size_t LHW  = (size_t)1024 * 512;          // 524,288 per (side,layer)

  unsigned short* nin   = ws;
  unsigned short* qkv   = nin + NIN;
  unsigned short* proj  = qkv;                     // aliases qkv (dead after attn)
  unsigned short* cb    = qkv + NQKV;              // (2,B,S2,D)
  unsigned short* hwx   = cb + 2 * NIN;            // (2,B,S,D)
  unsigned short* hwy   = hwx + 2 * MS;            // (2,B,S,D)
  unsigned short* WTall = hwy + 2 * MS;            // (3072,512)
  unsigned short* WTp   = WTall + 6 * DD;          // (2,512,512)
  unsigned short* hWT   = WTp + 2 * DD;            // (2,2,1024,512)
  float* qkvbias        = (float*)(hWT + 4 * LHW); // 3072 fp32

  // --- prep: 3 dispatches ---
  {
    dim3 ga(16, 16, 8);
    k_transpose_attn<<<ga, 256, 0, stream>>>(lW, rW, WTall, WTp);
    dim3 gh(32, 16, 4);
    k_transpose_hw<<<gh, 256, 0, stream>>>(lhwW, rhwW, hWT);
  }
  k_build_new_in<<<2092, 256, 0, stream>>>(x, lpad, rpad, lb, rb, nin, qkvbias);

  const int MQ = B_ * S2_;   // 8320

  // --- fused QKV both sides: (8320 x 3072) ---
  {
    dim3 g(3072 / 128, MQ / 128, 1);   // (24, 65)
    k_gemm_mfma<<<g, 256, 0, stream>>>(nin, 0, WTall, 0, qkvbias, qkvbias,
                                       qkv, 0, MQ, 3072, D_);
  }

  // --- attention, both sides ---
  k_attn_window<<<(2 * B_ * S2_) / 4, 256, 0, stream>>>(qkv, cb);

  // --- out-projection, z-batched over side ---
  {
    dim3 g(D_ / 128, MQ / 128, 2);     // (4, 65, 2)
    k_gemm_mfma<<<g, 256, 0, stream>>>(cb, NIN, WTp, DD, lb + 3 * D_, rb + 3 * D_,
                                       proj, NIN, MQ, D_, D_);
  }

  // --- rel add, z-batched ---
  {
    dim3 g(2048, 2);
    k_rel_add<<<g, 256, 0, stream>>>(proj, nin, lw, rw, hwx);
  }

  // --- highway layers: gemm + fused gate, z-batched over side ---
  {
    dim3 g(1024 / 128, (B_ * S_) / 128, 2);   // (8, 64, 2)
    k_gemm_hw<false><<<g, 256, 0, stream>>>(hwx, hWT, 2 * LHW,
                                            lhwb, rhwb, hwy, nullptr);
    k_gemm_hw<true><<<g, 256, 0, stream>>>(hwy, hWT + LHW, 2 * LHW,
                                           lhwb + 1024, rhwb + 1024,
                                           nullptr, out);
  }
}

// Round 7
// 243.948 us; speedup vs baseline: 6.2217x; 1.1023x over previous
//
#include <hip/hip_runtime.h>

// SelfAttentiveLBLBiLM on MI355X — round 7: 6 dispatches.
// r6 post-mortem: QKV 583 TF w/ 0 bank conflicts; remaining cost = gaps
// (9 dispatches), rel_add round-trip, prep scatter. Now:
//  - ctx compacted to (2,B,S,D): downstream rows all valid, proj M=8192
//  - rel_add fused into proj GEMM epilogue via LDS tile round-trip
//    (bf16 tile, pad 136 cols for 16B-aligned b128 re-read)
//  - one prep mega-kernel (attn transpose | hw transpose | build+bias)
// Dispatches: prep, qkv gemm, attn, proj+rel gemm, hw gemm x2.

#define B_ 8
#define S_ 1024
#define D_ 512
#define H_ 8
#define DK_ 64
#define WIDTH_ 8
#define S2_ 1040
#define NHW_ 2

typedef short bf16x8 __attribute__((ext_vector_type(8)));
typedef float f32x4 __attribute__((ext_vector_type(4)));

__device__ __forceinline__ float us2f(unsigned short u) {
  union { unsigned int i; float f; } c; c.i = ((unsigned int)u) << 16; return c.f;
}
__device__ __forceinline__ unsigned short f2us(float f) {
  union { float f; unsigned int i; } c; c.f = f;
  unsigned int x = c.i;
  return (unsigned short)((x + 0x7fffu + ((x >> 16) & 1u)) >> 16);
}
__device__ __forceinline__ unsigned int pack2(float a, float b) {
  return (unsigned int)f2us(a) | ((unsigned int)f2us(b) << 16);
}
__device__ __forceinline__ void async16(const void* g, void* l) {
  __builtin_amdgcn_global_load_lds(
      (const __attribute__((address_space(1))) void*)g,
      (__attribute__((address_space(3))) void*)l, 16, 0, 0);
}
__device__ __forceinline__ void unpack8(uint4 u, float* f) {
  unsigned int w[4] = {u.x, u.y, u.z, u.w};
  #pragma unroll
  for (int c = 0; c < 4; ++c) {
    union { unsigned int i; float g; } lo, hi;
    lo.i = w[c] << 16;
    hi.i = w[c] & 0xffff0000u;
    f[2 * c] = lo.g;
    f[2 * c + 1] = hi.g;
  }
}

// ---------------------------------------------------------------------------
// Prep mega-kernel. blockIdx.x ranges:
//  [0,2048): attn weight transpose, 8 slices (side=sl>>2, slice=sl&3), 16x16
//  [2048,4096): hw weight transpose+interleave, 4 slices, 32x16
//  [4096,6188): build new_in (+ qkv bias tail)
__global__ __launch_bounds__(256) void k_prep(
    const float* __restrict__ x,
    const float* __restrict__ lpad, const float* __restrict__ rpad,
    const float* __restrict__ lW, const float* __restrict__ rW,
    const float* __restrict__ lb, const float* __restrict__ rb,
    const float* __restrict__ lhwW, const float* __restrict__ rhwW,
    unsigned short* __restrict__ WTall, unsigned short* __restrict__ WTp,
    unsigned short* __restrict__ hWT,
    unsigned short* __restrict__ nin, float* __restrict__ qkvbias)
{
  __shared__ float tile[32][33];
  const size_t DD = (size_t)D_ * D_;
  int bx = blockIdx.x;
  int tx = threadIdx.x & 31, ty = threadIdx.x >> 5;

  if (bx < 2048) {                     // ---- attn transpose
    int sl = bx >> 8, rem = bx & 255;
    int side = sl >> 2, slice = sl & 3;
    int c0 = (rem & 15) * 32, r0 = (rem >> 4) * 32;
    const float* src = (side ? rW : lW) + (size_t)slice * DD;
    unsigned short* dst = (slice < 3) ? WTall + (size_t)(side * 3 + slice) * DD
                                      : WTp + (size_t)side * DD;
    #pragma unroll
    for (int i = 0; i < 4; ++i)
      tile[ty + i * 8][tx] = src[(size_t)(r0 + ty + i * 8) * D_ + c0 + tx];
    __syncthreads();
    #pragma unroll
    for (int i = 0; i < 4; ++i)
      dst[(size_t)(c0 + ty + i * 8) * D_ + r0 + tx] = f2us(tile[tx][ty + i * 8]);
    return;
  }
  if (bx < 4096) {                     // ---- hw transpose + interleave
    int idx = bx - 2048;
    int sl = idx >> 9, rem = idx & 511;    // sl: side*2+layer
    int c0 = (rem & 31) * 32, r0 = (rem >> 5) * 32;
    const float* src = ((sl >> 1) ? rhwW : lhwW) + (size_t)(sl & 1) * 512 * 1024;
    unsigned short* dst = hWT + (size_t)sl * 1024 * 512;
    #pragma unroll
    for (int i = 0; i < 4; ++i)
      tile[ty + i * 8][tx] = src[(size_t)(r0 + ty + i * 8) * 1024 + c0 + tx];
    __syncthreads();
    #pragma unroll
    for (int i = 0; i < 4; ++i) {
      int c = c0 + ty + i * 8;
      int q = (2 * ((c & 511) >> 4) + (c >= 512 ? 1 : 0)) * 16 + (c & 15);
      dst[(size_t)q * 512 + r0 + tx] = f2us(tile[tx][ty + i * 8]);
    }
    return;
  }
  // ---- build new_in + bias tail
  int gid = (bx - 4096) * 256 + threadIdx.x;
  const int NTH = B_ * S2_ * 64;       // 532,480
  if (gid >= NTH) {
    int t = gid - NTH;
    if (t < 1536) qkvbias[t] = lb[t];
    else if (t < 3072) qkvbias[t] = rb[t - 1536];
    return;
  }
  int c8 = (gid & 63) << 3;
  int row = gid >> 6;
  int b = row / S2_;
  int t = row - b * S2_;
  const float* src;
  if (t < WIDTH_)            src = lpad + (size_t)t * D_ + c8;
  else if (t >= S_ + WIDTH_) src = rpad + (size_t)(t - S_ - WIDTH_) * D_ + c8;
  else                       src = x + ((size_t)b * S_ + (t - WIDTH_)) * D_ + c8;
  float4 a = *reinterpret_cast<const float4*>(src);
  float4 c = *reinterpret_cast<const float4*>(src + 4);
  uint4 o;
  o.x = pack2(a.x, a.y); o.y = pack2(a.z, a.w);
  o.z = pack2(c.x, c.y); o.w = pack2(c.z, c.w);
  *reinterpret_cast<uint4*>(nin + (size_t)row * D_ + c8) = o;
}

// ---------------------------------------------------------------------------
// MFMA GEMM (QKV): C(M,N) = A(M,K) @ BT(N,K)^T + bias(N).
// BK=64, XOR-swizzled LDS, tile 128x128, 4 waves.
__global__ __launch_bounds__(256) void k_gemm_mfma(
    const unsigned short* __restrict__ A,
    const unsigned short* __restrict__ BT,
    const float* __restrict__ bias,
    unsigned short* __restrict__ C,
    int M, int N, int K)
{
  __shared__ unsigned short As[128 * 64];
  __shared__ unsigned short Bs[128 * 64];

  const int tid = threadIdx.x;
  const int w = tid >> 6;
  const int l = tid & 63;
  const int bm = blockIdx.y * 128;
  const int bn = blockIdx.x * 128;
  const int wrow = (w >> 1) * 64;
  const int wcol = (w & 1) * 64;

  const int lr = l >> 3;
  const int sk = (((l & 7) ^ lr) & 7) * 8;
  const unsigned short* Ap = A + (size_t)(bm + w * 8 + lr) * K + sk;
  const unsigned short* Bp = BT + (size_t)(bn + w * 8 + lr) * K + sk;
  unsigned short* lA = &As[w * 512];
  unsigned short* lB = &Bs[w * 512];
  const size_t K32 = (size_t)32 * K;

  const int fl = l & 15;
  const int fq = l >> 4;
  const int fx = fl & 7;

  f32x4 acc[4][4];
  #pragma unroll
  for (int mi = 0; mi < 4; ++mi)
    #pragma unroll
    for (int ni = 0; ni < 4; ++ni) acc[mi][ni] = (f32x4){0.f, 0.f, 0.f, 0.f};

  for (int k0 = 0; k0 < K; k0 += 64) {
    #pragma unroll
    for (int r = 0; r < 4; ++r) {
      async16(Ap + k0 + r * K32, lA + r * 2048);
      async16(Bp + k0 + r * K32, lB + r * 2048);
    }
    __syncthreads();
    #pragma unroll
    for (int s = 0; s < 2; ++s) {
      bf16x8 af[4], bfr[4];
      #pragma unroll
      for (int mi = 0; mi < 4; ++mi)
        af[mi] = *reinterpret_cast<const bf16x8*>(
            &As[(wrow + mi * 16 + fl) * 64 + (((s * 4 + fq) ^ fx) * 8)]);
      #pragma unroll
      for (int ni = 0; ni < 4; ++ni)
        bfr[ni] = *reinterpret_cast<const bf16x8*>(
            &Bs[(wcol + ni * 16 + fl) * 64 + (((s * 4 + fq) ^ fx) * 8)]);
      #pragma unroll
      for (int mi = 0; mi < 4; ++mi)
        #pragma unroll
        for (int ni = 0; ni < 4; ++ni)
          acc[mi][ni] = __builtin_amdgcn_mfma_f32_16x16x32_bf16(
              af[mi], bfr[ni], acc[mi][ni], 0, 0, 0);
    }
    __syncthreads();
  }

  float bv[4];
  #pragma unroll
  for (int ni = 0; ni < 4; ++ni) bv[ni] = bias[bn + wcol + ni * 16 + fl];

  const int rbase = (l >> 4) * 4;
  #pragma unroll
  for (int mi = 0; mi < 4; ++mi) {
    #pragma unroll
    for (int r = 0; r < 4; ++r) {
      int row = bm + wrow + mi * 16 + rbase + r;
      unsigned short* Cp = C + (size_t)row * N + bn + wcol + fl;
      #pragma unroll
      for (int ni = 0; ni < 4; ++ni)
        Cp[ni * 16] = f2us(acc[mi][ni][r] + bv[ni]);
    }
  }
}

// ---------------------------------------------------------------------------
// Proj GEMM + fused rel-add. A = ctx (2,8192,512) bf16 compacted; z = side.
// After K-loop: bias-added tile -> LDS (bf16, 128x136), barrier, cooperative
// re-read + 9-tap nin window + write hwx (2,8192,512).
__global__ __launch_bounds__(256) void k_gemm_proj(
    const unsigned short* __restrict__ ctx,
    const unsigned short* __restrict__ WTp,    // (2,512,512)
    const unsigned short* __restrict__ nin,    // (B,S2,512)
    const float* __restrict__ lb3, const float* __restrict__ rb3,
    const float* __restrict__ wrel0, const float* __restrict__ wrel1,
    unsigned short* __restrict__ hwx)          // (2,8192,512)
{
  __shared__ unsigned short smem[128 * 136];   // 34.8 KB; staging uses 32 KB
  unsigned short* As = smem;
  unsigned short* Bs = smem + 8192;
  const int K = 512, N = 512;
  const size_t MS = (size_t)B_ * S_ * D_;

  const int z = blockIdx.z;
  const unsigned short* A = ctx + (size_t)z * MS;
  const unsigned short* BT = WTp + (size_t)z * 512 * 512;
  const float* bias = z ? rb3 : lb3;
  const float* wrel = z ? wrel1 : wrel0;
  const int off = z * WIDTH_;

  const int tid = threadIdx.x;
  const int w = tid >> 6;
  const int l = tid & 63;
  const int bm = blockIdx.y * 128;
  const int bn = blockIdx.x * 128;
  const int wrow = (w >> 1) * 64;
  const int wcol = (w & 1) * 64;

  const int lr = l >> 3;
  const int sk = (((l & 7) ^ lr) & 7) * 8;
  const unsigned short* Ap = A + (size_t)(bm + w * 8 + lr) * K + sk;
  const unsigned short* Bp = BT + (size_t)(bn + w * 8 + lr) * K + sk;
  unsigned short* lA = &As[w * 512];
  unsigned short* lB = &Bs[w * 512];
  const size_t K32 = (size_t)32 * K;

  const int fl = l & 15;
  const int fq = l >> 4;
  const int fx = fl & 7;

  f32x4 acc[4][4];
  #pragma unroll
  for (int mi = 0; mi < 4; ++mi)
    #pragma unroll
    for (int ni = 0; ni < 4; ++ni) acc[mi][ni] = (f32x4){0.f, 0.f, 0.f, 0.f};

  for (int k0 = 0; k0 < K; k0 += 64) {
    #pragma unroll
    for (int r = 0; r < 4; ++r) {
      async16(Ap + k0 + r * K32, lA + r * 2048);
      async16(Bp + k0 + r * K32, lB + r * 2048);
    }
    __syncthreads();
    #pragma unroll
    for (int s = 0; s < 2; ++s) {
      bf16x8 af[4], bfr[4];
      #pragma unroll
      for (int mi = 0; mi < 4; ++mi)
        af[mi] = *reinterpret_cast<const bf16x8*>(
            &As[(wrow + mi * 16 + fl) * 64 + (((s * 4 + fq) ^ fx) * 8)]);
      #pragma unroll
      for (int ni = 0; ni < 4; ++ni)
        bfr[ni] = *reinterpret_cast<const bf16x8*>(
            &Bs[(wcol + ni * 16 + fl) * 64 + (((s * 4 + fq) ^ fx) * 8)]);
      #pragma unroll
      for (int mi = 0; mi < 4; ++mi)
        #pragma unroll
        for (int ni = 0; ni < 4; ++ni)
          acc[mi][ni] = __builtin_amdgcn_mfma_f32_16x16x32_bf16(
              af[mi], bfr[ni], acc[mi][ni], 0, 0, 0);
    }
    __syncthreads();
  }

  // stage bias-added tile into LDS (bf16, ld 136)
  float bv[4];
  #pragma unroll
  for (int ni = 0; ni < 4; ++ni) bv[ni] = bias[bn + wcol + ni * 16 + fl];
  const int rbase = (l >> 4) * 4;
  #pragma unroll
  for (int mi = 0; mi < 4; ++mi)
    #pragma unroll
    for (int r = 0; r < 4; ++r)
      #pragma unroll
      for (int ni = 0; ni < 4; ++ni)
        smem[(wrow + mi * 16 + rbase + r) * 136 + wcol + ni * 16 + fl] =
            f2us(acc[mi][ni][r] + bv[ni]);
  __syncthreads();

  // cooperative rel-add: 16 threads per tile row, 8-col chunks
  const int trow = tid >> 4;
  const int tcol = (tid & 15) * 8;
  const float w0 = wrel[0], w1 = wrel[1], w2 = wrel[2], w3 = wrel[3],
              w4 = wrel[4], w5 = wrel[5], w6 = wrel[6], w7 = wrel[7],
              w8 = wrel[8];
  const float wj[9] = {w0, w1, w2, w3, w4, w5, w6, w7, w8};
  #pragma unroll
  for (int i = 0; i < 8; ++i) {
    int r = trow + i * 16;
    int gr = bm + r;
    int b = gr >> 10, s = gr & (S_ - 1);
    float a8[8];
    unpack8(*reinterpret_cast<const uint4*>(&smem[r * 136 + tcol]), a8);
    const unsigned short* np =
        nin + ((size_t)b * S2_ + off + s) * D_ + bn + tcol;
    #pragma unroll
    for (int j = 0; j < 9; ++j) {
      float nf[8];
      unpack8(*reinterpret_cast<const uint4*>(np + (size_t)j * D_), nf);
      #pragma unroll
      for (int e = 0; e < 8; ++e) a8[e] += wj[j] * nf[e];
    }
    uint4 o;
    o.x = pack2(a8[0], a8[1]); o.y = pack2(a8[2], a8[3]);
    o.z = pack2(a8[4], a8[5]); o.w = pack2(a8[6], a8[7]);
    *reinterpret_cast<uint4*>(
        hwx + (size_t)z * MS + (size_t)gr * D_ + bn + tcol) = o;
  }
}

// ---------------------------------------------------------------------------
// Highway GEMM with fused gate epilogue (unchanged from r6).
template <bool FINAL>
__global__ __launch_bounds__(256) void k_gemm_hw(
    const unsigned short* __restrict__ Xsrc,
    const unsigned short* __restrict__ BT, size_t bStrZ,
    const float* __restrict__ bias0, const float* __restrict__ bias1,
    unsigned short* __restrict__ Obf,
    float* __restrict__ Ofp)
{
  __shared__ unsigned short As[128 * 64];
  __shared__ unsigned short Bs[128 * 64];
  const int K = 512;
  const size_t MS = (size_t)B_ * S_ * D_;

  const int z = blockIdx.z;
  const unsigned short* A = Xsrc + (size_t)z * MS;
  BT += (size_t)z * bStrZ;
  const float* bias = z ? bias1 : bias0;

  const int tid = threadIdx.x;
  const int w = tid >> 6;
  const int l = tid & 63;
  const int bm = blockIdx.y * 128;
  const int bn = blockIdx.x * 128;
  const int wrow = (w >> 1) * 64;
  const int wcol = (w & 1) * 64;

  const int lr = l >> 3;
  const int sk = (((l & 7) ^ lr) & 7) * 8;
  const unsigned short* Ap = A + (size_t)(bm + w * 8 + lr) * K + sk;
  const unsigned short* Bp = BT + (size_t)(bn + w * 8 + lr) * K + sk;
  unsigned short* lA = &As[w * 512];
  unsigned short* lB = &Bs[w * 512];
  const size_t K32 = (size_t)32 * K;

  const int fl = l & 15;
  const int fq = l >> 4;
  const int fx = fl & 7;

  f32x4 acc[4][4];
  #pragma unroll
  for (int mi = 0; mi < 4; ++mi)
    #pragma unroll
    for (int ni = 0; ni < 4; ++ni) acc[mi][ni] = (f32x4){0.f, 0.f, 0.f, 0.f};

  for (int k0 = 0; k0 < K; k0 += 64) {
    #pragma unroll
    for (int r = 0; r < 4; ++r) {
      async16(Ap + k0 + r * K32, lA + r * 2048);
      async16(Bp + k0 + r * K32, lB + r * 2048);
    }
    __syncthreads();
    #pragma unroll
    for (int s = 0; s < 2; ++s) {
      bf16x8 af[4], bfr[4];
      #pragma unroll
      for (int mi = 0; mi < 4; ++mi)
        af[mi] = *reinterpret_cast<const bf16x8*>(
            &As[(wrow + mi * 16 + fl) * 64 + (((s * 4 + fq) ^ fx) * 8)]);
      #pragma unroll
      for (int ni = 0; ni < 4; ++ni)
        bfr[ni] = *reinterpret_cast<const bf16x8*>(
            &Bs[(wcol + ni * 16 + fl) * 64 + (((s * 4 + fq) ^ fx) * 8)]);
      #pragma unroll
      for (int mi = 0; mi < 4; ++mi)
        #pragma unroll
        for (int ni = 0; ni < 4; ++ni)
          acc[mi][ni] = __builtin_amdgcn_mfma_f32_16x16x32_bf16(
              af[mi], bfr[ni], acc[mi][ni], 0, 0, 0);
    }
    __syncthreads();
  }

  const int ocb = ((bn + wcol) >> 1) + fl;
  float bnl[2], bg[2];
  #pragma unroll
  for (int p = 0; p < 2; ++p) {
    bnl[p] = bias[ocb + p * 16];
    bg[p]  = bias[512 + ocb + p * 16];
  }

  const int rbase = (l >> 4) * 4;
  #pragma unroll
  for (int mi = 0; mi < 4; ++mi) {
    #pragma unroll
    for (int r = 0; r < 4; ++r) {
      int row = bm + wrow + mi * 16 + rbase + r;
      #pragma unroll
      for (int p = 0; p < 2; ++p) {
        int oc = ocb + p * 16;
        float nl = fmaxf(acc[mi][2 * p][r] + bnl[p], 0.f);
        float g  = 1.f / (1.f + __expf(-(acc[mi][2 * p + 1][r] + bg[p])));
        float xv = us2f(A[(size_t)row * 512 + oc]);
        float res = g * xv + (1.f - g) * nl;
        if (FINAL) Ofp[(size_t)row * 1024 + z * 512 + oc] = res;
        else       Obf[(size_t)z * MS + (size_t)row * 512 + oc] = f2us(res);
      }
    }
  }
}

// ---------------------------------------------------------------------------
// Windowed attention, compacted output. Wave = (dir, b, s), i = s + WIDTH.
// qkv ld 3072: dir*1536 + {q:0,k:512,v:1024}. ctx: (2,B,S,512).
__global__ __launch_bounds__(256) void k_attn_window(
    const unsigned short* __restrict__ qkv,
    unsigned short* __restrict__ ctx)
{
  int wid = (blockIdx.x * 256 + threadIdx.x) >> 6;   // dir*B*S + b*S + s
  int lane = threadIdx.x & 63;
  int s = wid & (S_ - 1);
  int b = (wid >> 10) & (B_ - 1);
  int dir = wid >> 13;
  int i = s + WIDTH_;

  const size_t base = (size_t)b * S2_ * 3072 + dir * 1536;
  const int c0 = lane * 8;

  float qf[8];
  unpack8(*reinterpret_cast<const uint4*>(qkv + base + (size_t)i * 3072 + c0), qf);

  float sc[10];
  float mx = -1e30f;
  #pragma unroll
  for (int t = 0; t < 10; ++t) {
    int j = (dir == 0) ? (i - 9 + t) : (i + t);
    float sv = -1e30f;
    if (j >= 0 && j < S2_) {
      float kf[8];
      unpack8(*reinterpret_cast<const uint4*>(
          qkv + base + (size_t)j * 3072 + 512 + c0), kf);
      float p = qf[0] * kf[0];
      #pragma unroll
      for (int e = 1; e < 8; ++e) p += qf[e] * kf[e];
      p += __shfl_xor(p, 1);
      p += __shfl_xor(p, 2);
      p += __shfl_xor(p, 4);
      sv = p * 0.125f;
    }
    sc[t] = sv;
    mx = fmaxf(mx, sv);
  }

  float denom = 0.f;
  #pragma unroll
  for (int t = 0; t < 10; ++t) {
    sc[t] = (sc[t] > -1e29f) ? __expf(sc[t] - mx) : 0.f;
    denom += sc[t];
  }
  float inv = 1.f / denom;

  float acc[8] = {0.f, 0.f, 0.f, 0.f, 0.f, 0.f, 0.f, 0.f};
  #pragma unroll
  for (int t = 0; t < 10; ++t) {
    int j = (dir == 0) ? (i - 9 + t) : (i + t);
    if (j >= 0 && j < S2_) {
      float vf[8];
      unpack8(*reinterpret_cast<const uint4*>(
          qkv + base + (size_t)j * 3072 + 1024 + c0), vf);
      float p = sc[t];
      #pragma unroll
      for (int e = 0; e < 8; ++e) acc[e] += p * vf[e];
    }
  }

  uint4 o;
  o.x = pack2(acc[0] * inv, acc[1] * inv);
  o.y = pack2(acc[2] * inv, acc[3] * inv);
  o.z = pack2(acc[4] * inv, acc[5] * inv);
  o.w = pack2(acc[6] * inv, acc[7] * inv);
  *reinterpret_cast<uint4*>(
      ctx + (((size_t)dir * B_ + b) * S_ + s) * D_ + c0) = o;
}

// ---------------------------------------------------------------------------
extern "C" void kernel_launch(void* const* d_in, const int* in_sizes, int n_in,
                              void* d_out, int out_size, void* d_ws, size_t ws_size,
                              hipStream_t stream) {
  const float* x    = (const float*)d_in[0];
  const float* lW   = (const float*)d_in[1];
  const float* lb   = (const float*)d_in[2];
  const float* rW   = (const float*)d_in[3];
  const float* rb   = (const float*)d_in[4];
  const float* lpad = (const float*)d_in[5];
  const float* rpad = (const float*)d_in[6];
  const float* lw   = (const float*)d_in[7];
  const float* rw   = (const float*)d_in[8];
  const float* lhwW = (const float*)d_in[9];
  const float* lhwb = (const float*)d_in[10];
  const float* rhwW = (const float*)d_in[11];
  const float* rhwb = (const float*)d_in[12];
  float* out = (float*)d_out;
  unsigned short* ws = (unsigned short*)d_ws;

  const size_t NIN  = (size_t)B_ * S2_ * D_;       // 4,259,840
  const size_t NQKV = (size_t)B_ * S2_ * 3072;     // 25,559,040
  const size_t MS   = (size_t)B_ * S_ * D_;        // 4,194,304
  const size_t DD   = (size_t)D_ * D_;             // 262,144
  const size_t LHW  = (size_t)1024 * 512;          // 524,288

  unsigned short* nin   = ws;
  unsigned short* qkv   = nin + NIN;
  unsigned short* ctx   = qkv + NQKV;              // (2,B,S,D)
  unsigned short* hwx   = ctx + 2 * MS;            // (2,B,S,D)
  unsigned short* hwy   = hwx + 2 * MS;            // (2,B,S,D)
  unsigned short* WTall = hwy + 2 * MS;            // (3072,512)
  unsigned short* WTp   = WTall + 6 * DD;          // (2,512,512)
  unsigned short* hWT   = WTp + 2 * DD;            // (2,2,1024,512)
  float* qkvbias        = (float*)(hWT + 4 * LHW); // 3072 fp32

  // --- prep: 1 dispatch ---
  k_prep<<<6188, 256, 0, stream>>>(x, lpad, rpad, lW, rW, lb, rb, lhwW, rhwW,
                                   WTall, WTp, hWT, nin, qkvbias);

  const int MQ = B_ * S2_;   // 8320

  // --- fused QKV both sides: (8320 x 3072) ---
  {
    dim3 g(3072 / 128, MQ / 128, 1);   // (24, 65)
    k_gemm_mfma<<<g, 256, 0, stream>>>(nin, WTall, qkvbias, qkv, MQ, 3072, D_);
  }

  // --- attention, both sides, compacted ctx ---
  k_attn_window<<<(2 * B_ * S_) / 4, 256, 0, stream>>>(qkv, ctx);

  // --- proj + fused rel-add, z-batched over side ---
  {
    dim3 g(D_ / 128, (B_ * S_) / 128, 2);   // (4, 64, 2)
    k_gemm_proj<<<g, 256, 0, stream>>>(ctx, WTp, nin, lb + 3 * D_, rb + 3 * D_,
                                       lw, rw, hwx);
  }

  // --- highway layers: gemm + fused gate, z-batched over side ---
  {
    dim3 g(1024 / 128, (B_ * S_) / 128, 2);   // (8, 64, 2)
    k_gemm_hw<false><<<g, 256, 0, stream>>>(hwx, hWT, 2 * LHW,
                                            lhwb, rhwb, hwy, nullptr);
    k_gemm_hw<true><<<g, 256, 0, stream>>>(hwy, hWT + LHW, 2 * LHW,
                                           lhwb + 1024, rhwb + 1024,
                                           nullptr, out);
  }
}